// Round 7
// baseline (248.369 us; speedup 1.0000x reference)
//
#include <hip/hip_runtime.h>
#include <math.h>

// Problem constants
#define BATCH 2
#define SEQ   1024
#define DMODEL 512
#define NHEAD 8
#define HDIM  64
#define FFND  2048
#define BH    (BATCH*NHEAD)   // 16

typedef float  f32x4   __attribute__((ext_vector_type(4)));
typedef float  f32x16  __attribute__((ext_vector_type(16)));
typedef __bf16 bf16x8  __attribute__((ext_vector_type(8)));

#define WAITVM(n) asm volatile("s_waitcnt vmcnt(" #n ")" ::: "memory")

__device__ __forceinline__ unsigned short f2bf(float f) {
  union { __bf16 h; unsigned short u; } z; z.h = (__bf16)f; return z.u;
}
__device__ __forceinline__ float bf2f(unsigned short h) {
  union { unsigned u; float f; } x; x.u = ((unsigned)h) << 16;
  return x.f;
}
__device__ __forceinline__ unsigned pk2(float a, float b) {
  union { __bf16 h[2]; unsigned u; } z;
  z.h[0] = (__bf16)a; z.h[1] = (__bf16)b; return z.u;
}
__device__ __forceinline__ float gelu_f(float v) {
  float u = 0.7978845608f * (v + 0.044715f * v * v * v);
  float a = fabsf(u);
  float e = __expf(-2.f * a);
  float t = (1.f - e) / (1.f + e);
  t = copysignf(t, u);
  return 0.5f * v * (1.f + t);
}

__device__ __forceinline__ void load_lds16(const void* g, void* l) {
  __builtin_amdgcn_global_load_lds((const __attribute__((address_space(1))) void*)g,
                                   (__attribute__((address_space(3))) void*)l, 16, 0, 0);
}

// ---------------------------------------------------------------- prep ----
__global__ __launch_bounds__(256) void prep_misc(
    const float* __restrict__ x, const float* __restrict__ bq,
    const float* __restrict__ bk, const float* __restrict__ bv,
    unsigned short* __restrict__ xb, float* __restrict__ bqkv) {
  int gid = blockIdx.x * 256 + threadIdx.x;
  float4 v = ((const float4*)x)[gid];
  ushort4 s;
  s.x = f2bf(v.x); s.y = f2bf(v.y); s.z = f2bf(v.z); s.w = f2bf(v.w);
  ((ushort4*)xb)[gid] = s;
  if (gid < 1536)
    bqkv[gid] = gid < 512 ? bq[gid] : (gid < 1024 ? bk[gid - 512] : bv[gid - 1024]);
}

// all weight transposes fused: src f32 [R][C] -> dst bf16 [C][R]. block (32,8).
__global__ __launch_bounds__(256) void prep_weights(
    const float* __restrict__ Wq, const float* __restrict__ Wk,
    const float* __restrict__ Wv, const float* __restrict__ Wo,
    const float* __restrict__ F1, const float* __restrict__ F2,
    unsigned short* __restrict__ qkvT, unsigned short* __restrict__ WoT,
    unsigned short* __restrict__ F1T, unsigned short* __restrict__ F2T) {
  __shared__ float t[32][33];
  int bid = blockIdx.x;
  const float* src; unsigned short* dst; int R, C, tx, ty;
  if (bid < 1024) {
    int m = bid >> 8;
    src = m == 0 ? Wq : m == 1 ? Wk : m == 2 ? Wv : Wo;
    dst = m < 3 ? qkvT + m * 512 * 512 : WoT;
    R = 512; C = 512; int u = bid & 255; tx = u & 15; ty = u >> 4;
  } else if (bid < 2048) {
    src = F1; dst = F1T; R = 512; C = 2048;
    int u = bid - 1024; tx = u & 63; ty = u >> 6;
  } else {
    src = F2; dst = F2T; R = 2048; C = 512;
    int u = bid - 2048; tx = u & 15; ty = u >> 4;
  }
  int c0 = tx * 32, r0 = ty * 32;
  int x_ = threadIdx.x, y_ = threadIdx.y;
#pragma unroll
  for (int i = 0; i < 4; i++)
    t[y_ + i * 8][x_] = src[(size_t)(r0 + y_ + i * 8) * C + c0 + x_];
  __syncthreads();
#pragma unroll
  for (int i = 0; i < 4; i++)
    dst[(size_t)(c0 + y_ + i * 8) * R + r0 + x_] = f2bf(t[x_][y_ + i * 8]);
}

// ---------------------------------------------------------------- RPE -----
// v4: prefetch rel across chunks; GEMM1 32x32x16 (K=4+bias); hidden via
// wave-private swizzled LDS; GEMM2 16x16x32; DIRECT coalesced-ish output
// stores (lane holds 4 consecutive j of one head).
__global__ __launch_bounds__(256) void rpe_mfma(
    const float* __restrict__ rel, const float* __restrict__ R1,
    const float* __restrict__ rb1, const float* __restrict__ R2,
    const float* __restrict__ rb2, unsigned short* __restrict__ rpe) {
  __shared__ unsigned short Hs[4][32 * 64];   // 4KB per wave
  const int tid = threadIdx.x, lane = tid & 63, w = tid >> 6;
  const int l31 = lane & 31, hi = lane >> 5;
  const int l15 = lane & 15, l4g = lane >> 4;
  char* Hw = (char*)&Hs[w][0];

  bf16x8 a1[2];
#pragma unroll
  for (int mt = 0; mt < 2; mt++) {
    bf16x8 z = {};
    if (hi == 0) {
      int d = mt * 32 + l31;
      z[0] = (__bf16)R1[0 * 64 + d];
      z[1] = (__bf16)R1[1 * 64 + d];
      z[2] = (__bf16)R1[2 * 64 + d];
      z[3] = (__bf16)R1[3 * 64 + d];
      z[4] = (__bf16)rb1[d];
    }
    a1[mt] = z;
  }
  bf16x8 b2f[2];
#pragma unroll
  for (int ks = 0; ks < 2; ks++) {
    bf16x8 z = {};
    if (l15 < 8) {
#pragma unroll
      for (int j = 0; j < 8; j++)
        z[j] = (__bf16)R2[(ks * 32 + l4g * 8 + j) * 8 + l15];
    }
    b2f[ks] = z;
  }
  float rb2v = (l15 < 8) ? rb2[l15] : 0.f;

  const int wgid = blockIdx.x * 4 + w;          // 8192 waves
  float4 rv = {};
  if (hi == 0) rv = *(const float4*)&rel[(size_t)(wgid * 32 + l31) * 4];

  for (int c = 0; c < 8; c++) {
    int p0 = (wgid + c * 8192) * 32;            // 32-row chunk base
    float4 rc = rv;
    if (c < 7 && hi == 0)
      rv = *(const float4*)&rel[(size_t)((wgid + (c + 1) * 8192) * 32 + l31) * 4];

    bf16x8 b1 = {};
    if (hi == 0) {
      b1[0] = (__bf16)rc.x; b1[1] = (__bf16)rc.y;
      b1[2] = (__bf16)rc.z; b1[3] = (__bf16)rc.w;
      b1[4] = (__bf16)1.0f;
    }
    // GEMM1 + ReLU + pack to swizzled LDS
    const int g1w = ((l31 & 7) ^ (l31 >> 3)) << 4;
#pragma unroll
    for (int mt = 0; mt < 2; mt++) {
      f32x16 hz = {};
      f32x16 h = __builtin_amdgcn_mfma_f32_32x32x16_bf16(a1[mt], b1, hz, 0, 0, 0);
#pragma unroll
      for (int q = 0; q < 4; q++) {
        float v0 = fmaxf(h[4 * q + 0], 0.f), v1 = fmaxf(h[4 * q + 1], 0.f);
        float v2 = fmaxf(h[4 * q + 2], 0.f), v3 = fmaxf(h[4 * q + 3], 0.f);
        uint2 pk; pk.x = pk2(v0, v1); pk.y = pk2(v2, v3);
        int byte = (l31 * 128 + mt * 64 + q * 16 + hi * 8) ^ g1w;
        *(uint2*)(Hw + byte) = pk;
      }
    }
    // GEMM2
    f32x4 acc2[2];
    acc2[0] = (f32x4){0.f, 0.f, 0.f, 0.f};
    acc2[1] = (f32x4){0.f, 0.f, 0.f, 0.f};
#pragma unroll
    for (int mt2 = 0; mt2 < 2; mt2++) {
      int row = mt2 * 16 + l15;
      int gr = ((row & 7) ^ (row >> 3)) << 4;
#pragma unroll
      for (int ks = 0; ks < 2; ks++) {
        int byte = row * 128 + (((ks * 4 + l4g) << 4) ^ gr);
        bf16x8 af = *(const bf16x8*)(Hw + byte);
        acc2[mt2] = __builtin_amdgcn_mfma_f32_16x16x32_bf16(af, b2f[ks], acc2[mt2], 0, 0, 0);
      }
    }
    // direct store: lane (h=l15<8, l4g, mt2) holds 4 consecutive j of head h
    if (l15 < 8) {
      int b = p0 >> 20, ij0 = (p0 & 1048575);
      size_t base = ((size_t)(b * 8 + l15) << 20) + ij0;
#pragma unroll
      for (int mt2 = 0; mt2 < 2; mt2++) {
        uint2 pk;
        pk.x = pk2(acc2[mt2][0] + rb2v, acc2[mt2][1] + rb2v);
        pk.y = pk2(acc2[mt2][2] + rb2v, acc2[mt2][3] + rb2v);
        *(uint2*)&rpe[base + mt2 * 16 + l4g * 4] = pk;
      }
    }
  }
}

// ---------------------------------------------------------------- GEMM ----
enum { EPI_F32 = 0, EPI_GELU = 1, EPI_QKV = 2 };

template <int EPI, int BMt, int BNt, int WM, int WN>
__global__ __launch_bounds__(256) void gemm_bt(
    const unsigned short* __restrict__ A, const unsigned short* __restrict__ Bt,
    const float* __restrict__ bias, void* __restrict__ O0, void* __restrict__ O1,
    void* __restrict__ O2, int M, int N, int K) {
  __shared__ unsigned short As[2][BMt * 64];
  __shared__ unsigned short Bs[2][BNt * 64];
  const int tid = threadIdx.x, lane = tid & 63, w = tid >> 6;
  const int wr = w >> 1, wc = w & 1;
  const int m0 = blockIdx.y * BMt, n0 = blockIdx.x * BNt;
  const int l15 = lane & 15, l4g = lane >> 4;
  constexpr int NL = BMt / 32 + BNt / 32;

  f32x4 acc[WM][WN];
#pragma unroll
  for (int i = 0; i < WM; i++)
#pragma unroll
    for (int j = 0; j < WN; j++) acc[i][j] = (f32x4){0.f, 0.f, 0.f, 0.f};

  auto stage = [&](int buf, int kt) {
#pragma unroll
    for (int it = 0; it < BMt / 32; ++it) {
      int c = it * 256 + tid, row = c >> 3;
      int s16 = (c & 7) ^ (row & 7);
      load_lds16(A + (size_t)(m0 + row) * K + kt * 64 + s16 * 8,
                 (char*)&As[buf][0] + c * 16);
    }
#pragma unroll
    for (int it = 0; it < BNt / 32; ++it) {
      int c = it * 256 + tid, row = c >> 3;
      int s16 = (c & 7) ^ (row & 7);
      load_lds16(Bt + (size_t)(n0 + row) * K + kt * 64 + s16 * 8,
                 (char*)&Bs[buf][0] + c * 16);
    }
  };

  const int nkt = K / 64;
  stage(0, 0);
  for (int kt = 0; kt < nkt; ++kt) {
    const int cur = kt & 1;
    if (kt + 1 < nkt) {
      stage(cur ^ 1, kt + 1);
      if constexpr (NL == 6) WAITVM(6); else WAITVM(4);
    } else {
      WAITVM(0);
    }
    __builtin_amdgcn_s_barrier();
#pragma unroll
    for (int kk = 0; kk < 2; ++kk) {
      bf16x8 af[WM], bfv[WN];
#pragma unroll
      for (int i = 0; i < WM; i++) {
        int row = wr * (WM * 16) + i * 16 + l15;
        af[i] = *(const bf16x8*)((char*)&As[cur][0] + row * 128 +
                                 (((kk * 4 + l4g) ^ (row & 7)) << 4));
      }
#pragma unroll
      for (int j = 0; j < WN; j++) {
        int row = wc * (WN * 16) + j * 16 + l15;
        bfv[j] = *(const bf16x8*)((char*)&Bs[cur][0] + row * 128 +
                                  (((kk * 4 + l4g) ^ (row & 7)) << 4));
      }
#pragma unroll
      for (int i = 0; i < WM; i++)
#pragma unroll
        for (int j = 0; j < WN; j++)
          acc[i][j] = __builtin_amdgcn_mfma_f32_16x16x32_bf16(af[i], bfv[j], acc[i][j], 0, 0, 0);
    }
    if (kt + 1 < nkt) {
      asm volatile("" ::: "memory");
      __builtin_amdgcn_s_barrier();
    }
  }

#pragma unroll
  for (int i = 0; i < WM; i++) {
    int row = m0 + wr * (WM * 16) + i * 16 + l4g * 4;
#pragma unroll
    for (int j = 0; j < WN; j++) {
      int col = n0 + wc * (WN * 16) + j * 16 + l15;
      float bv = bias ? bias[col] : 0.f;
#pragma unroll
      for (int r = 0; r < 4; r++) {
        float v = acc[i][j][r] + bv;
        int rr = row + r;
        if (EPI == EPI_F32) {
          ((float*)O0)[(size_t)rr * N + col] = v;
        } else if (EPI == EPI_GELU) {
          ((unsigned short*)O0)[(size_t)rr * N + col] = f2bf(gelu_f(v));
        } else {  // QKV scatter
          int b = rr >> 10, n = rr & 1023;
          int d = col & 511, h = d >> 6, hd = d & 63;
          int bh = b * 8 + h;
          unsigned short bv16 = f2bf(v);
          if (col < 512)
            ((unsigned short*)O0)[((size_t)bh * 1024 + n) * 64 + hd] = bv16;
          else if (col < 1024)
            ((unsigned short*)O1)[((size_t)bh * 1024 + n) * 64 + hd] = bv16;
          else
            ((unsigned short*)O2)[((size_t)bh * 64 + hd) * 1024 + n] = bv16;
        }
      }
    }
  }
}

// ------------------------------------------------------------- attention --
// 128-thread blocks, 32-row q-tiles, grid 512 -> 3 blocks/CU (44KB LDS).
__global__ __launch_bounds__(128) void attn_kernel(
    const unsigned short* __restrict__ Qh, const unsigned short* __restrict__ Kh,
    const unsigned short* __restrict__ VT, const unsigned short* __restrict__ rpe,
    unsigned short* __restrict__ AO) {
  __shared__ unsigned short Ks[2][64 * 64], Vs[2][64 * 64];
  __shared__ unsigned short Rs[2][32 * 64];
  __shared__ unsigned short Ps[2][16 * 64];
  const int tid = threadIdx.x, lane = tid & 63, w = tid >> 6;
  const int l15 = lane & 15, l4g = lane >> 4;
  const int bid = blockIdx.x;
  const int it = (bid >> 3) & 31;
  const int bh = (bid & 7) | (((bid >> 8) & 1) << 3);
  const int i0 = it * 32;
  const unsigned short* Qb = Qh + (size_t)bh * SEQ * HDIM;
  const unsigned short* Kb = Kh + (size_t)bh * SEQ * HDIM;
  const unsigned short* Vb = VT + (size_t)bh * HDIM * SEQ;
  const unsigned short* Rb = rpe + ((size_t)bh << 20);

  bf16x8 qf[2];
#pragma unroll
  for (int kk = 0; kk < 2; kk++)
    qf[kk] = *(const bf16x8*)&Qb[(size_t)(i0 + w * 16 + l15) * 64 + kk * 32 + l4g * 8];

  f32x4 o[4];
#pragma unroll
  for (int i = 0; i < 4; i++) o[i] = (f32x4){0.f, 0.f, 0.f, 0.f};
  float m4[4], l4s[4];
#pragma unroll
  for (int r = 0; r < 4; r++) { m4[r] = -1e30f; l4s[r] = 0.f; }

  auto stage = [&](int buf, int jt) {
    int j0 = jt * 64;
#pragma unroll
    for (int itn = 0; itn < 4; ++itn) {
      int c = itn * 128 + tid, row = c >> 3;
      int s8 = ((c & 7) ^ (row & 7)) * 8;
      load_lds16(Kb + (size_t)(j0 + row) * 64 + s8, (char*)&Ks[buf][0] + c * 16);
    }
#pragma unroll
    for (int itn = 0; itn < 4; ++itn) {
      int c = itn * 128 + tid, row = c >> 3;
      int s8 = ((c & 7) ^ (row & 7)) * 8;
      load_lds16(Vb + (size_t)row * SEQ + j0 + s8, (char*)&Vs[buf][0] + c * 16);
    }
#pragma unroll
    for (int itn = 0; itn < 2; ++itn) {
      int c = itn * 128 + tid, row = c >> 3;
      int s8 = ((c & 7) ^ (row & 7)) * 8;
      load_lds16(Rb + (size_t)(i0 + row) * SEQ + j0 + s8, (char*)&Rs[buf][0] + c * 16);
    }
  };

  stage(0, 0);
  for (int jt = 0; jt < 16; ++jt) {
    const int cur = jt & 1;
    if (jt < 15) {
      stage(cur ^ 1, jt + 1);
      WAITVM(10);
    } else {
      WAITVM(0);
    }
    __builtin_amdgcn_s_barrier();

    f32x4 sa[4];
#pragma unroll
    for (int js = 0; js < 4; js++) sa[js] = (f32x4){0.f, 0.f, 0.f, 0.f};
    __builtin_amdgcn_s_setprio(1);
#pragma unroll
    for (int kk = 0; kk < 2; kk++) {
#pragma unroll
      for (int js = 0; js < 4; js++) {
        int row = js * 16 + l15;
        bf16x8 kb = *(const bf16x8*)((char*)&Ks[cur][0] + row * 128 +
                                     (((kk * 4 + l4g) ^ (row & 7)) << 4));
        sa[js] = __builtin_amdgcn_mfma_f32_16x16x32_bf16(qf[kk], kb, sa[js], 0, 0, 0);
      }
    }
    __builtin_amdgcn_s_setprio(0);
    float p[4][4], mx[4];
#pragma unroll
    for (int r = 0; r < 4; r++) mx[r] = -1e30f;
#pragma unroll
    for (int js = 0; js < 4; js++)
#pragma unroll
      for (int r = 0; r < 4; r++) {
        int row = w * 16 + l4g * 4 + r;
        int byte = row * 128 + ((((js * 2) + (l15 >> 3)) ^ (row & 7)) << 4) + ((l15 & 7) << 1);
        float rv = bf2f(*(const unsigned short*)((const char*)&Rs[cur][0] + byte));
        float s = sa[js][r] * 0.125f + rv;
        p[js][r] = s;
        mx[r] = fmaxf(mx[r], s);
      }
#pragma unroll
    for (int off = 1; off < 16; off <<= 1)
#pragma unroll
      for (int r = 0; r < 4; r++) mx[r] = fmaxf(mx[r], __shfl_xor(mx[r], off));
    float al[4], sm[4];
#pragma unroll
    for (int r = 0; r < 4; r++) {
      float nm = fmaxf(m4[r], mx[r]);
      al[r] = __expf(m4[r] - nm);
      m4[r] = nm;
      sm[r] = 0.f;
    }
#pragma unroll
    for (int js = 0; js < 4; js++)
#pragma unroll
      for (int r = 0; r < 4; r++) {
        float e = __expf(p[js][r] - m4[r]);
        p[js][r] = e;
        sm[r] += e;
      }
#pragma unroll
    for (int off = 1; off < 16; off <<= 1)
#pragma unroll
      for (int r = 0; r < 4; r++) sm[r] += __shfl_xor(sm[r], off);
#pragma unroll
    for (int r = 0; r < 4; r++) l4s[r] = l4s[r] * al[r] + sm[r];
#pragma unroll
    for (int hdf = 0; hdf < 4; hdf++)
#pragma unroll
      for (int r = 0; r < 4; r++) o[hdf][r] *= al[r];
#pragma unroll
    for (int js = 0; js < 4; js++)
#pragma unroll
      for (int r = 0; r < 4; r++) {
        int row = l4g * 4 + r;
        int byte = row * 128 + ((((js * 2) + (l15 >> 3)) ^ (row & 7)) << 4) + ((l15 & 7) << 1);
        *(unsigned short*)((char*)&Ps[w][0] + byte) = f2bf(p[js][r]);
      }
    __builtin_amdgcn_s_setprio(1);
#pragma unroll
    for (int kk = 0; kk < 2; kk++) {
      bf16x8 pf = *(const bf16x8*)((char*)&Ps[w][0] + l15 * 128 +
                                   (((kk * 4 + l4g) ^ (l15 & 7)) << 4));
#pragma unroll
      for (int hdf = 0; hdf < 4; hdf++) {
        int row = hdf * 16 + l15;
        bf16x8 vb = *(const bf16x8*)((char*)&Vs[cur][0] + row * 128 +
                                     (((kk * 4 + l4g) ^ (row & 7)) << 4));
        o[hdf] = __builtin_amdgcn_mfma_f32_16x16x32_bf16(pf, vb, o[hdf], 0, 0, 0);
      }
    }
    __builtin_amdgcn_s_setprio(0);
    if (jt < 15) {
      asm volatile("" ::: "memory");
      __builtin_amdgcn_s_barrier();
    }
  }
  const int b = bh >> 3, h = bh & 7;
#pragma unroll
  for (int hdf = 0; hdf < 4; hdf++)
#pragma unroll
    for (int r = 0; r < 4; r++) {
      float v = o[hdf][r] / l4s[r];
      int n = i0 + w * 16 + l4g * 4 + r;
      AO[((size_t)b * SEQ + n) * DMODEL + h * 64 + hdf * 16 + l15] = f2bf(v);
    }
}

// ---------------------------------------------------------------- LN ------
__global__ __launch_bounds__(256) void ln_kernel(
    const float* __restrict__ a, const float* __restrict__ res,
    const float* __restrict__ g, const float* __restrict__ be,
    float* __restrict__ outf, unsigned short* __restrict__ outb) {
  const int row = blockIdx.x, t = threadIdx.x;
  const float* pa = a + (size_t)row * DMODEL;
  const float* pb = res + (size_t)row * DMODEL;
  float v0 = pa[t] + pb[t];
  float v1 = pa[t + 256] + pb[t + 256];
  float s = v0 + v1, sq = v0 * v0 + v1 * v1;
#pragma unroll
  for (int off = 1; off < 64; off <<= 1) {
    s += __shfl_xor(s, off);
    sq += __shfl_xor(sq, off);
  }
  __shared__ float ls[4], lq[4];
  int w = t >> 6, lane = t & 63;
  if (lane == 0) { ls[w] = s; lq[w] = sq; }
  __syncthreads();
  s = ls[0] + ls[1] + ls[2] + ls[3];
  sq = lq[0] + lq[1] + lq[2] + lq[3];
  float mu = s * (1.f / DMODEL);
  float var = sq * (1.f / DMODEL) - mu * mu;
  float rs = rsqrtf(var + 1e-5f);
  float y0 = (v0 - mu) * rs * g[t] + be[t];
  float y1v = (v1 - mu) * rs * g[t + 256] + be[t + 256];
  outf[(size_t)row * DMODEL + t] = y0;
  outf[(size_t)row * DMODEL + t + 256] = y1v;
  if (outb) {
    outb[(size_t)row * DMODEL + t] = f2bf(y0);
    outb[(size_t)row * DMODEL + t + 256] = f2bf(y1v);
  }
}

// ---------------------------------------------------------------- launch --
extern "C" void kernel_launch(void* const* d_in, const int* in_sizes, int n_in,
                              void* d_out, int out_size, void* d_ws, size_t ws_size,
                              hipStream_t stream) {
  const float* x   = (const float*)d_in[0];
  const float* rel = (const float*)d_in[1];
  const float* Wq  = (const float*)d_in[2];
  const float* bq  = (const float*)d_in[3];
  const float* Wk  = (const float*)d_in[4];
  const float* bk  = (const float*)d_in[5];
  const float* Wv  = (const float*)d_in[6];
  const float* bv  = (const float*)d_in[7];
  const float* Wo  = (const float*)d_in[8];
  const float* bo  = (const float*)d_in[9];
  const float* R1  = (const float*)d_in[10];
  const float* rb1 = (const float*)d_in[11];
  const float* R2  = (const float*)d_in[12];
  const float* rb2 = (const float*)d_in[13];
  const float* g1  = (const float*)d_in[14];
  const float* b1  = (const float*)d_in[15];
  const float* g2  = (const float*)d_in[16];
  const float* b2  = (const float*)d_in[17];
  const float* F1  = (const float*)d_in[18];
  const float* fb1 = (const float*)d_in[19];
  const float* F2  = (const float*)d_in[20];
  const float* fb2 = (const float*)d_in[21];

  char* p = (char*)d_ws;
  auto alloc = [&](size_t bytes) {
    char* r = p;
    p += (bytes + 255) & ~(size_t)255;
    return r;
  };
  unsigned short* xb   = (unsigned short*)alloc((size_t)2048 * 512 * 2);
  unsigned short* qkvT = (unsigned short*)alloc((size_t)1536 * 512 * 2);
  float*          bqkv = (float*)alloc(1536 * 4);
  unsigned short* WoT  = (unsigned short*)alloc((size_t)512 * 512 * 2);
  unsigned short* F1T  = (unsigned short*)alloc((size_t)2048 * 512 * 2);
  unsigned short* F2T  = (unsigned short*)alloc((size_t)512 * 2048 * 2);
  unsigned short* Qhp  = (unsigned short*)alloc((size_t)BH * SEQ * HDIM * 2);
  unsigned short* Khp  = (unsigned short*)alloc((size_t)BH * SEQ * HDIM * 2);
  unsigned short* VTp  = (unsigned short*)alloc((size_t)BH * HDIM * SEQ * 2);
  unsigned short* rpep = (unsigned short*)alloc((size_t)BH * SEQ * SEQ * 2);   // 32MB
  unsigned short* attO = (unsigned short*)alloc((size_t)2048 * 512 * 2);
  float*          t1   = (float*)alloc((size_t)2048 * 512 * 4);
  float*          y1   = (float*)alloc((size_t)2048 * 512 * 4);
  unsigned short* y1b  = (unsigned short*)alloc((size_t)2048 * 512 * 2);
  float*          t2   = t1;                     // t1 dead after LN1
  unsigned short* hbuf = rpep;                   // rpe dead after attention

  prep_misc<<<1024, 256, 0, stream>>>(x, bq, bk, bv, xb, bqkv);
  prep_weights<<<3072, dim3(32, 8), 0, stream>>>(Wq, Wk, Wv, Wo, F1, F2,
                                                 qkvT, WoT, F1T, F2T);
  rpe_mfma<<<2048, 256, 0, stream>>>(rel, R1, rb1, R2, rb2, rpep);

  // QKV: 128x64 tiles -> 384 blocks
  gemm_bt<EPI_QKV, 128, 64, 4, 2><<<dim3(24, 16), 256, 0, stream>>>(
      xb, qkvT, bqkv, Qhp, Khp, VTp, 2048, 1536, 512);
  attn_kernel<<<512, 128, 0, stream>>>(Qhp, Khp, VTp, rpep, attO);

  // Wo: 64x64 tiles -> 256 blocks
  gemm_bt<EPI_F32, 64, 64, 2, 2><<<dim3(8, 32), 256, 0, stream>>>(
      attO, WoT, bo, t1, nullptr, nullptr, 2048, 512, 512);
  ln_kernel<<<2048, 256, 0, stream>>>(x, t1, g1, b1, y1, y1b);

  // FFN1: 128x64 tiles -> 512 blocks
  gemm_bt<EPI_GELU, 128, 64, 4, 2><<<dim3(32, 16), 256, 0, stream>>>(
      y1b, F1T, fb1, hbuf, nullptr, nullptr, 2048, 2048, 512);
  // FFN2: 64x64 tiles -> 256 blocks
  gemm_bt<EPI_F32, 64, 64, 2, 2><<<dim3(8, 32), 256, 0, stream>>>(
      hbuf, F2T, fb2, t2, nullptr, nullptr, 2048, 512, 2048);
  ln_kernel<<<2048, 256, 0, stream>>>(y1, t2, g2, b2, (float*)d_out, nullptr);
}

// Round 8
// 234.481 us; speedup vs baseline: 1.0592x; 1.0592x over previous
//
#include <hip/hip_runtime.h>
#include <math.h>

// Problem constants
#define BATCH 2
#define SEQ   1024
#define DMODEL 512
#define NHEAD 8
#define HDIM  64
#define FFND  2048
#define BH    (BATCH*NHEAD)   // 16

typedef float  f32x4   __attribute__((ext_vector_type(4)));
typedef float  f32x16  __attribute__((ext_vector_type(16)));
typedef __bf16 bf16x8  __attribute__((ext_vector_type(8)));

#define WAITVM(n) asm volatile("s_waitcnt vmcnt(" #n ")" ::: "memory")

__device__ __forceinline__ unsigned short f2bf(float f) {
  union { __bf16 h; unsigned short u; } z; z.h = (__bf16)f; return z.u;
}
__device__ __forceinline__ float bf2f(unsigned short h) {
  union { unsigned u; float f; } x; x.u = ((unsigned)h) << 16;
  return x.f;
}
__device__ __forceinline__ unsigned pk2(float a, float b) {
  union { __bf16 h[2]; unsigned u; } z;
  z.h[0] = (__bf16)a; z.h[1] = (__bf16)b; return z.u;
}
__device__ __forceinline__ float gelu_f(float v) {
  float u = 0.7978845608f * (v + 0.044715f * v * v * v);
  float a = fabsf(u);
  float e = __expf(-2.f * a);
  float t = (1.f - e) / (1.f + e);
  t = copysignf(t, u);
  return 0.5f * v * (1.f + t);
}

__device__ __forceinline__ void load_lds16(const void* g, void* l) {
  __builtin_amdgcn_global_load_lds((const __attribute__((address_space(1))) void*)g,
                                   (__attribute__((address_space(3))) void*)l, 16, 0, 0);
}

// ---------------------------------------------------------------- prep ----
__global__ __launch_bounds__(256) void prep_misc(
    const float* __restrict__ x, const float* __restrict__ bq,
    const float* __restrict__ bk, const float* __restrict__ bv,
    unsigned short* __restrict__ xb, float* __restrict__ bqkv) {
  int gid = blockIdx.x * 256 + threadIdx.x;
  float4 v = ((const float4*)x)[gid];
  ushort4 s;
  s.x = f2bf(v.x); s.y = f2bf(v.y); s.z = f2bf(v.z); s.w = f2bf(v.w);
  ((ushort4*)xb)[gid] = s;
  if (gid < 1536)
    bqkv[gid] = gid < 512 ? bq[gid] : (gid < 1024 ? bk[gid - 512] : bv[gid - 1024]);
}

// all weight transposes fused: src f32 [R][C] -> dst bf16 [C][R]. block (32,8).
__global__ __launch_bounds__(256) void prep_weights(
    const float* __restrict__ Wq, const float* __restrict__ Wk,
    const float* __restrict__ Wv, const float* __restrict__ Wo,
    const float* __restrict__ F1, const float* __restrict__ F2,
    unsigned short* __restrict__ qkvT, unsigned short* __restrict__ WoT,
    unsigned short* __restrict__ F1T, unsigned short* __restrict__ F2T) {
  __shared__ float t[32][33];
  int bid = blockIdx.x;
  const float* src; unsigned short* dst; int R, C, tx, ty;
  if (bid < 1024) {
    int m = bid >> 8;
    src = m == 0 ? Wq : m == 1 ? Wk : m == 2 ? Wv : Wo;
    dst = m < 3 ? qkvT + m * 512 * 512 : WoT;
    R = 512; C = 512; int u = bid & 255; tx = u & 15; ty = u >> 4;
  } else if (bid < 2048) {
    src = F1; dst = F1T; R = 512; C = 2048;
    int u = bid - 1024; tx = u & 63; ty = u >> 6;
  } else {
    src = F2; dst = F2T; R = 2048; C = 512;
    int u = bid - 2048; tx = u & 15; ty = u >> 4;
  }
  int c0 = tx * 32, r0 = ty * 32;
  int x_ = threadIdx.x, y_ = threadIdx.y;
#pragma unroll
  for (int i = 0; i < 4; i++)
    t[y_ + i * 8][x_] = src[(size_t)(r0 + y_ + i * 8) * C + c0 + x_];
  __syncthreads();
#pragma unroll
  for (int i = 0; i < 4; i++)
    dst[(size_t)(c0 + y_ + i * 8) * R + r0 + x_] = f2bf(t[x_][y_ + i * 8]);
}

// ---------------------------------------------------------------- RPE -----
// v4 + log2(e) pre-scale folded into R2/rb2 (rpe feeds only softmax scores).
__global__ __launch_bounds__(256) void rpe_mfma(
    const float* __restrict__ rel, const float* __restrict__ R1,
    const float* __restrict__ rb1, const float* __restrict__ R2,
    const float* __restrict__ rb2, unsigned short* __restrict__ rpe) {
  __shared__ unsigned short Hs[4][32 * 64];   // 4KB per wave
  const int tid = threadIdx.x, lane = tid & 63, w = tid >> 6;
  const int l31 = lane & 31, hi = lane >> 5;
  const int l15 = lane & 15, l4g = lane >> 4;
  const float LOG2E = 1.4426950408889634f;
  char* Hw = (char*)&Hs[w][0];

  bf16x8 a1[2];
#pragma unroll
  for (int mt = 0; mt < 2; mt++) {
    bf16x8 z = {};
    if (hi == 0) {
      int d = mt * 32 + l31;
      z[0] = (__bf16)R1[0 * 64 + d];
      z[1] = (__bf16)R1[1 * 64 + d];
      z[2] = (__bf16)R1[2 * 64 + d];
      z[3] = (__bf16)R1[3 * 64 + d];
      z[4] = (__bf16)rb1[d];
    }
    a1[mt] = z;
  }
  bf16x8 b2f[2];
#pragma unroll
  for (int ks = 0; ks < 2; ks++) {
    bf16x8 z = {};
    if (l15 < 8) {
#pragma unroll
      for (int j = 0; j < 8; j++)
        z[j] = (__bf16)(R2[(ks * 32 + l4g * 8 + j) * 8 + l15] * LOG2E);
    }
    b2f[ks] = z;
  }
  float rb2v = (l15 < 8) ? rb2[l15] * LOG2E : 0.f;

  const int wgid = blockIdx.x * 4 + w;          // 8192 waves
  float4 rv = {};
  if (hi == 0) rv = *(const float4*)&rel[(size_t)(wgid * 32 + l31) * 4];

  for (int c = 0; c < 8; c++) {
    int p0 = (wgid + c * 8192) * 32;            // 32-row chunk base
    float4 rc = rv;
    if (c < 7 && hi == 0)
      rv = *(const float4*)&rel[(size_t)((wgid + (c + 1) * 8192) * 32 + l31) * 4];

    bf16x8 b1 = {};
    if (hi == 0) {
      b1[0] = (__bf16)rc.x; b1[1] = (__bf16)rc.y;
      b1[2] = (__bf16)rc.z; b1[3] = (__bf16)rc.w;
      b1[4] = (__bf16)1.0f;
    }
    const int g1w = ((l31 & 7) ^ (l31 >> 3)) << 4;
#pragma unroll
    for (int mt = 0; mt < 2; mt++) {
      f32x16 hz = {};
      f32x16 h = __builtin_amdgcn_mfma_f32_32x32x16_bf16(a1[mt], b1, hz, 0, 0, 0);
#pragma unroll
      for (int q = 0; q < 4; q++) {
        float v0 = fmaxf(h[4 * q + 0], 0.f), v1 = fmaxf(h[4 * q + 1], 0.f);
        float v2 = fmaxf(h[4 * q + 2], 0.f), v3 = fmaxf(h[4 * q + 3], 0.f);
        uint2 pk; pk.x = pk2(v0, v1); pk.y = pk2(v2, v3);
        int byte = (l31 * 128 + mt * 64 + q * 16 + hi * 8) ^ g1w;
        *(uint2*)(Hw + byte) = pk;
      }
    }
    f32x4 acc2[2];
    acc2[0] = (f32x4){0.f, 0.f, 0.f, 0.f};
    acc2[1] = (f32x4){0.f, 0.f, 0.f, 0.f};
#pragma unroll
    for (int mt2 = 0; mt2 < 2; mt2++) {
      int row = mt2 * 16 + l15;
      int gr = ((row & 7) ^ (row >> 3)) << 4;
#pragma unroll
      for (int ks = 0; ks < 2; ks++) {
        int byte = row * 128 + (((ks * 4 + l4g) << 4) ^ gr);
        bf16x8 af = *(const bf16x8*)(Hw + byte);
        acc2[mt2] = __builtin_amdgcn_mfma_f32_16x16x32_bf16(af, b2f[ks], acc2[mt2], 0, 0, 0);
      }
    }
    if (l15 < 8) {
      int b = p0 >> 20, ij0 = (p0 & 1048575);
      size_t base = ((size_t)(b * 8 + l15) << 20) + ij0;
#pragma unroll
      for (int mt2 = 0; mt2 < 2; mt2++) {
        uint2 pk;
        pk.x = pk2(acc2[mt2][0] + rb2v, acc2[mt2][1] + rb2v);
        pk.y = pk2(acc2[mt2][2] + rb2v, acc2[mt2][3] + rb2v);
        *(uint2*)&rpe[base + mt2 * 16 + l4g * 4] = pk;
      }
    }
  }
}

// ---------------------------------------------------------------- GEMM ----
enum { EPI_F32 = 0, EPI_GELU = 1, EPI_QKV = 2 };

template <int EPI, int BMt, int BNt, int WM, int WN>
__global__ __launch_bounds__(256) void gemm_bt(
    const unsigned short* __restrict__ A, const unsigned short* __restrict__ Bt,
    const float* __restrict__ bias, void* __restrict__ O0, void* __restrict__ O1,
    void* __restrict__ O2, int M, int N, int K) {
  __shared__ unsigned short As[2][BMt * 64];
  __shared__ unsigned short Bs[2][BNt * 64];
  const int tid = threadIdx.x, lane = tid & 63, w = tid >> 6;
  const int wr = w >> 1, wc = w & 1;
  const int m0 = blockIdx.y * BMt, n0 = blockIdx.x * BNt;
  const int l15 = lane & 15, l4g = lane >> 4;
  constexpr int NL = BMt / 32 + BNt / 32;

  f32x4 acc[WM][WN];
#pragma unroll
  for (int i = 0; i < WM; i++)
#pragma unroll
    for (int j = 0; j < WN; j++) acc[i][j] = (f32x4){0.f, 0.f, 0.f, 0.f};

  auto stage = [&](int buf, int kt) {
#pragma unroll
    for (int it = 0; it < BMt / 32; ++it) {
      int c = it * 256 + tid, row = c >> 3;
      int s16 = (c & 7) ^ (row & 7);
      load_lds16(A + (size_t)(m0 + row) * K + kt * 64 + s16 * 8,
                 (char*)&As[buf][0] + c * 16);
    }
#pragma unroll
    for (int it = 0; it < BNt / 32; ++it) {
      int c = it * 256 + tid, row = c >> 3;
      int s16 = (c & 7) ^ (row & 7);
      load_lds16(Bt + (size_t)(n0 + row) * K + kt * 64 + s16 * 8,
                 (char*)&Bs[buf][0] + c * 16);
    }
  };

  const int nkt = K / 64;
  stage(0, 0);
  for (int kt = 0; kt < nkt; ++kt) {
    const int cur = kt & 1;
    if (kt + 1 < nkt) {
      stage(cur ^ 1, kt + 1);
      if constexpr (NL == 6) WAITVM(6); else WAITVM(4);
    } else {
      WAITVM(0);
    }
    __builtin_amdgcn_s_barrier();
#pragma unroll
    for (int kk = 0; kk < 2; ++kk) {
      bf16x8 af[WM], bfv[WN];
#pragma unroll
      for (int i = 0; i < WM; i++) {
        int row = wr * (WM * 16) + i * 16 + l15;
        af[i] = *(const bf16x8*)((char*)&As[cur][0] + row * 128 +
                                 (((kk * 4 + l4g) ^ (row & 7)) << 4));
      }
#pragma unroll
      for (int j = 0; j < WN; j++) {
        int row = wc * (WN * 16) + j * 16 + l15;
        bfv[j] = *(const bf16x8*)((char*)&Bs[cur][0] + row * 128 +
                                  (((kk * 4 + l4g) ^ (row & 7)) << 4));
      }
#pragma unroll
      for (int i = 0; i < WM; i++)
#pragma unroll
        for (int j = 0; j < WN; j++)
          acc[i][j] = __builtin_amdgcn_mfma_f32_16x16x32_bf16(af[i], bfv[j], acc[i][j], 0, 0, 0);
    }
    if (kt + 1 < nkt) {
      asm volatile("" ::: "memory");
      __builtin_amdgcn_s_barrier();
    }
  }

#pragma unroll
  for (int i = 0; i < WM; i++) {
    int row = m0 + wr * (WM * 16) + i * 16 + l4g * 4;
#pragma unroll
    for (int j = 0; j < WN; j++) {
      int col = n0 + wc * (WN * 16) + j * 16 + l15;
      float bv = bias ? bias[col] : 0.f;
#pragma unroll
      for (int r = 0; r < 4; r++) {
        float v = acc[i][j][r] + bv;
        int rr = row + r;
        if (EPI == EPI_F32) {
          ((float*)O0)[(size_t)rr * N + col] = v;
        } else if (EPI == EPI_GELU) {
          ((unsigned short*)O0)[(size_t)rr * N + col] = f2bf(gelu_f(v));
        } else {  // QKV scatter
          int b = rr >> 10, n = rr & 1023;
          int d = col & 511, h = d >> 6, hd = d & 63;
          int bh = b * 8 + h;
          unsigned short bv16 = f2bf(v);
          if (col < 512)
            ((unsigned short*)O0)[((size_t)bh * 1024 + n) * 64 + hd] = bv16;
          else if (col < 1024)
            ((unsigned short*)O1)[((size_t)bh * 1024 + n) * 64 + hd] = bv16;
          else
            ((unsigned short*)O2)[((size_t)bh * 64 + hd) * 1024 + n] = bv16;
        }
      }
    }
  }
}

// ------------------------------------------------------------- attention --
// v5: swapped-operand QK/PV (q on column axis), no-max exp2 softmax (scores
// bounded; rpe pre-scaled by log2e), wave-private P LDS [q][kj], KV-split x2
// with additive partial combine. grid 512, 256 thr, 56KB LDS -> 2 blocks/CU.
__global__ __launch_bounds__(256, 2) void attn_kernel(
    const unsigned short* __restrict__ Qh, const unsigned short* __restrict__ Kh,
    const unsigned short* __restrict__ VT, const unsigned short* __restrict__ rpe,
    float* __restrict__ oP, float* __restrict__ lP) {
  __shared__ unsigned short Ks[2][64 * 64], Vs[2][64 * 64], Rs[2][64 * 64];
  __shared__ unsigned short Ps[4][16 * 64];
  const int tid = threadIdx.x, lane = tid & 63, w = tid >> 6;
  const int l15 = lane & 15, l4g = lane >> 4;
  const int bid = blockIdx.x;
  const int it = (bid >> 3) & 15;
  const int bh = (bid & 7) | (((bid >> 7) & 1) << 3);
  const int kv = (bid >> 8) & 1;
  const int i0 = it * 64;
  const float C = 0.18033688011112042f;  // 0.125 * log2(e)
  const unsigned short* Qb = Qh + (size_t)bh * SEQ * HDIM;
  const unsigned short* Kb = Kh + (size_t)bh * SEQ * HDIM;
  const unsigned short* Vb = VT + (size_t)bh * HDIM * SEQ;
  const unsigned short* Rb = rpe + ((size_t)bh << 20);
  char* Pw = (char*)&Ps[w][0];

  bf16x8 qf[2];
#pragma unroll
  for (int kk = 0; kk < 2; kk++)
    qf[kk] = *(const bf16x8*)&Qb[(size_t)(i0 + w * 16 + l15) * 64 + kk * 32 + l4g * 8];

  f32x4 o[4];
#pragma unroll
  for (int i = 0; i < 4; i++) o[i] = (f32x4){0.f, 0.f, 0.f, 0.f};
  float lsum = 0.f;

  auto stage = [&](int buf, int jt) {
    int j0 = jt * 64;
#pragma unroll
    for (int itn = 0; itn < 2; ++itn) {
      int c = itn * 256 + tid, row = c >> 3;
      int s8 = ((c & 7) ^ (row & 7)) * 8;
      load_lds16(Kb + (size_t)(j0 + row) * 64 + s8, (char*)&Ks[buf][0] + c * 16);
      load_lds16(Vb + (size_t)row * SEQ + j0 + s8, (char*)&Vs[buf][0] + c * 16);
      load_lds16(Rb + (size_t)(i0 + row) * SEQ + j0 + s8, (char*)&Rs[buf][0] + c * 16);
    }
  };

  stage(0, kv * 8);
  for (int jtl = 0; jtl < 8; ++jtl) {
    const int cur = jtl & 1;
    if (jtl < 7) {
      stage(cur ^ 1, kv * 8 + jtl + 1);
      WAITVM(6);
    } else {
      WAITVM(0);
    }
    __builtin_amdgcn_s_barrier();

    // QK^T swapped: saT[js] = K_js^T-tile x Q -> D[row=kj][col=q=l15]
    f32x4 sa[4];
#pragma unroll
    for (int js = 0; js < 4; js++) sa[js] = (f32x4){0.f, 0.f, 0.f, 0.f};
    __builtin_amdgcn_s_setprio(1);
#pragma unroll
    for (int kk = 0; kk < 2; kk++) {
#pragma unroll
      for (int js = 0; js < 4; js++) {
        int row = js * 16 + l15;
        bf16x8 kb = *(const bf16x8*)((char*)&Ks[cur][0] + row * 128 +
                                     (((kk * 4 + l4g) ^ (row & 7)) << 4));
        sa[js] = __builtin_amdgcn_mfma_f32_16x16x32_bf16(kb, qf[kk], sa[js], 0, 0, 0);
      }
    }
    __builtin_amdgcn_s_setprio(0);

    // p = exp2(sa*C + rpe_scaled); per-lane partial sum; pack P[q][kj] to LDS
    const int rrow = w * 16 + l15;
    const int rswz = (rrow & 7) << 4;
    const int pswz = (l15 & 7) << 4;
#pragma unroll
    for (int js = 0; js < 4; js++) {
      int rbyte = rrow * 128 + ((((js * 2) + (l4g >> 1)) << 4) ^ rswz) + ((l4g & 1) << 3);
      uint2 rv2 = *(const uint2*)((const char*)&Rs[cur][0] + rbyte);
      float p0 = exp2f(sa[js][0] * C + bf2f((unsigned short)(rv2.x & 0xffff)));
      float p1 = exp2f(sa[js][1] * C + bf2f((unsigned short)(rv2.x >> 16)));
      float p2 = exp2f(sa[js][2] * C + bf2f((unsigned short)(rv2.y & 0xffff)));
      float p3 = exp2f(sa[js][3] * C + bf2f((unsigned short)(rv2.y >> 16)));
      lsum += (p0 + p1) + (p2 + p3);
      uint2 pk; pk.x = pk2(p0, p1); pk.y = pk2(p2, p3);
      *(uint2*)(Pw + l15 * 128 + (((js * 32 + l4g * 8)) ^ pswz)) = pk;
    }

    // PV swapped: o[hdf] += V^T-tile x P^T -> D[row=hd][col=q=l15]
    __builtin_amdgcn_s_setprio(1);
#pragma unroll
    for (int kk = 0; kk < 2; kk++) {
      bf16x8 pf = *(const bf16x8*)(Pw + l15 * 128 + ((kk * 64 + l4g * 16) ^ pswz));
#pragma unroll
      for (int hdf = 0; hdf < 4; hdf++) {
        int row = hdf * 16 + l15;
        bf16x8 vb = *(const bf16x8*)((char*)&Vs[cur][0] + row * 128 +
                                     (((kk * 4 + l4g) ^ (row & 7)) << 4));
        o[hdf] = __builtin_amdgcn_mfma_f32_16x16x32_bf16(vb, pf, o[hdf], 0, 0, 0);
      }
    }
    __builtin_amdgcn_s_setprio(0);
    if (jtl < 7) {
      asm volatile("" ::: "memory");
      __builtin_amdgcn_s_barrier();
    }
  }

  // reduce lsum across l4g groups (same q = l15)
  lsum += __shfl_xor(lsum, 16);
  lsum += __shfl_xor(lsum, 32);

  const int b = bh >> 3, h = bh & 7;
  const int nrow = b * SEQ + i0 + w * 16 + l15;
#pragma unroll
  for (int hdf = 0; hdf < 4; hdf++)
    *(f32x4*)&oP[(size_t)kv * 2048 * 512 + (size_t)nrow * 512 +
                 h * 64 + hdf * 16 + l4g * 4] = o[hdf];
  if (l4g == 0)
    lP[kv * 16384 + bh * 1024 + i0 + w * 16 + l15] = lsum;
}

// combine: out = (o0+o1)/(l0+l1), bf16
__global__ __launch_bounds__(256) void attn_combine(
    const float* __restrict__ oP, const float* __restrict__ lP,
    unsigned short* __restrict__ AO) {
  const int n = blockIdx.x, t = threadIdx.x;
  float2 a = *(const float2*)&oP[(size_t)n * 512 + t * 2];
  float2 c = *(const float2*)&oP[(size_t)(2048 + n) * 512 + t * 2];
  int bh = (n >> 10) * 8 + (t >> 5), nq = n & 1023;
  float l = lP[bh * 1024 + nq] + lP[16384 + bh * 1024 + nq];
  float inv = 1.f / l;
  ((unsigned*)AO)[(size_t)n * 256 + t] = pk2((a.x + c.x) * inv, (a.y + c.y) * inv);
}

// ---------------------------------------------------------------- LN ------
__global__ __launch_bounds__(256) void ln_kernel(
    const float* __restrict__ a, const float* __restrict__ res,
    const float* __restrict__ g, const float* __restrict__ be,
    float* __restrict__ outf, unsigned short* __restrict__ outb) {
  const int row = blockIdx.x, t = threadIdx.x;
  const float* pa = a + (size_t)row * DMODEL;
  const float* pb = res + (size_t)row * DMODEL;
  float v0 = pa[t] + pb[t];
  float v1 = pa[t + 256] + pb[t + 256];
  float s = v0 + v1, sq = v0 * v0 + v1 * v1;
#pragma unroll
  for (int off = 1; off < 64; off <<= 1) {
    s += __shfl_xor(s, off);
    sq += __shfl_xor(sq, off);
  }
  __shared__ float ls[4], lq[4];
  int w = t >> 6, lane = t & 63;
  if (lane == 0) { ls[w] = s; lq[w] = sq; }
  __syncthreads();
  s = ls[0] + ls[1] + ls[2] + ls[3];
  sq = lq[0] + lq[1] + lq[2] + lq[3];
  float mu = s * (1.f / DMODEL);
  float var = sq * (1.f / DMODEL) - mu * mu;
  float rs = rsqrtf(var + 1e-5f);
  float y0 = (v0 - mu) * rs * g[t] + be[t];
  float y1v = (v1 - mu) * rs * g[t + 256] + be[t + 256];
  outf[(size_t)row * DMODEL + t] = y0;
  outf[(size_t)row * DMODEL + t + 256] = y1v;
  if (outb) {
    outb[(size_t)row * DMODEL + t] = f2bf(y0);
    outb[(size_t)row * DMODEL + t + 256] = f2bf(y1v);
  }
}

// ---------------------------------------------------------------- launch --
extern "C" void kernel_launch(void* const* d_in, const int* in_sizes, int n_in,
                              void* d_out, int out_size, void* d_ws, size_t ws_size,
                              hipStream_t stream) {
  const float* x   = (const float*)d_in[0];
  const float* rel = (const float*)d_in[1];
  const float* Wq  = (const float*)d_in[2];
  const float* bq  = (const float*)d_in[3];
  const float* Wk  = (const float*)d_in[4];
  const float* bk  = (const float*)d_in[5];
  const float* Wv  = (const float*)d_in[6];
  const float* bv  = (const float*)d_in[7];
  const float* Wo  = (const float*)d_in[8];
  const float* bo  = (const float*)d_in[9];
  const float* R1  = (const float*)d_in[10];
  const float* rb1 = (const float*)d_in[11];
  const float* R2  = (const float*)d_in[12];
  const float* rb2 = (const float*)d_in[13];
  const float* g1  = (const float*)d_in[14];
  const float* b1  = (const float*)d_in[15];
  const float* g2  = (const float*)d_in[16];
  const float* b2  = (const float*)d_in[17];
  const float* F1  = (const float*)d_in[18];
  const float* fb1 = (const float*)d_in[19];
  const float* F2  = (const float*)d_in[20];
  const float* fb2 = (const float*)d_in[21];

  char* p = (char*)d_ws;
  auto alloc = [&](size_t bytes) {
    char* r = p;
    p += (bytes + 255) & ~(size_t)255;
    return r;
  };
  unsigned short* xb   = (unsigned short*)alloc((size_t)2048 * 512 * 2);
  unsigned short* qkvT = (unsigned short*)alloc((size_t)1536 * 512 * 2);
  float*          bqkv = (float*)alloc(1536 * 4);
  unsigned short* WoT  = (unsigned short*)alloc((size_t)512 * 512 * 2);
  unsigned short* F1T  = (unsigned short*)alloc((size_t)2048 * 512 * 2);
  unsigned short* F2T  = (unsigned short*)alloc((size_t)512 * 2048 * 2);
  unsigned short* Qhp  = (unsigned short*)alloc((size_t)BH * SEQ * HDIM * 2);
  unsigned short* Khp  = (unsigned short*)alloc((size_t)BH * SEQ * HDIM * 2);
  unsigned short* VTp  = (unsigned short*)alloc((size_t)BH * HDIM * SEQ * 2);
  unsigned short* rpep = (unsigned short*)alloc((size_t)BH * SEQ * SEQ * 2);   // 32MB
  unsigned short* attO = (unsigned short*)alloc((size_t)2048 * 512 * 2);
  float*          t1   = (float*)alloc((size_t)2048 * 512 * 4);
  float*          y1   = (float*)alloc((size_t)2048 * 512 * 4);
  unsigned short* y1b  = (unsigned short*)alloc((size_t)2048 * 512 * 2);
  float*          t2   = t1;                     // t1 dead after LN1
  unsigned short* hbuf = rpep;                   // rpe dead after attention
  float*          oP   = t1;                     // t1+y1 (8MB) free during attn
  float*          lP   = (float*)y1b;            // y1b free during attn

  prep_misc<<<1024, 256, 0, stream>>>(x, bq, bk, bv, xb, bqkv);
  prep_weights<<<3072, dim3(32, 8), 0, stream>>>(Wq, Wk, Wv, Wo, F1, F2,
                                                 qkvT, WoT, F1T, F2T);
  rpe_mfma<<<2048, 256, 0, stream>>>(rel, R1, rb1, R2, rb2, rpep);

  // QKV: 128x64 tiles -> 384 blocks
  gemm_bt<EPI_QKV, 128, 64, 4, 2><<<dim3(24, 16), 256, 0, stream>>>(
      xb, qkvT, bqkv, Qhp, Khp, VTp, 2048, 1536, 512);
  attn_kernel<<<512, 256, 0, stream>>>(Qhp, Khp, VTp, rpep, oP, lP);
  attn_combine<<<2048, 256, 0, stream>>>(oP, lP, attO);

  // Wo: 64x64 tiles -> 256 blocks
  gemm_bt<EPI_F32, 64, 64, 2, 2><<<dim3(8, 32), 256, 0, stream>>>(
      attO, WoT, bo, t1, nullptr, nullptr, 2048, 512, 512);
  ln_kernel<<<2048, 256, 0, stream>>>(x, t1, g1, b1, y1, y1b);

  // FFN1: 128x64 tiles -> 512 blocks
  gemm_bt<EPI_GELU, 128, 64, 4, 2><<<dim3(32, 16), 256, 0, stream>>>(
      y1b, F1T, fb1, hbuf, nullptr, nullptr, 2048, 2048, 512);
  // FFN2: 64x64 tiles -> 256 blocks
  gemm_bt<EPI_F32, 64, 64, 2, 2><<<dim3(8, 32), 256, 0, stream>>>(
      hbuf, F2T, fb2, t2, nullptr, nullptr, 2048, 512, 2048);
  ln_kernel<<<2048, 256, 0, stream>>>(y1, t2, g2, b2, (float*)d_out, nullptr);
}

// Round 9
// 218.692 us; speedup vs baseline: 1.1357x; 1.0722x over previous
//
#include <hip/hip_runtime.h>
#include <math.h>

// Problem constants
#define BATCH 2
#define SEQ   1024
#define DMODEL 512
#define NHEAD 8
#define HDIM  64
#define FFND  2048
#define BH    (BATCH*NHEAD)   // 16

typedef float  f32x4   __attribute__((ext_vector_type(4)));
typedef float  f32x16  __attribute__((ext_vector_type(16)));
typedef __bf16 bf16x8  __attribute__((ext_vector_type(8)));

#define WAITVM(n) asm volatile("s_waitcnt vmcnt(" #n ")" ::: "memory")

__device__ __forceinline__ unsigned short f2bf(float f) {
  union { __bf16 h; unsigned short u; } z; z.h = (__bf16)f; return z.u;
}
__device__ __forceinline__ float bf2f(unsigned short h) {
  union { unsigned u; float f; } x; x.u = ((unsigned)h) << 16;
  return x.f;
}
__device__ __forceinline__ unsigned pk2(float a, float b) {
  union { __bf16 h[2]; unsigned u; } z;
  z.h[0] = (__bf16)a; z.h[1] = (__bf16)b; return z.u;
}
__device__ __forceinline__ float gelu_f(float v) {
  float u = 0.7978845608f * (v + 0.044715f * v * v * v);
  float a = fabsf(u);
  float e = __expf(-2.f * a);
  float t = (1.f - e) / (1.f + e);
  t = copysignf(t, u);
  return 0.5f * v * (1.f + t);
}

__device__ __forceinline__ void load_lds16(const void* g, void* l) {
  __builtin_amdgcn_global_load_lds((const __attribute__((address_space(1))) void*)g,
                                   (__attribute__((address_space(3))) void*)l, 16, 0, 0);
}

// ---------------------------------------------------------------- prep ----
// bid<1024: x->bf16 cast (+bias pack). bid>=1024: weight transpose-casts.
__global__ __launch_bounds__(256) void prep_all(
    const float* __restrict__ x, const float* __restrict__ bq,
    const float* __restrict__ bk, const float* __restrict__ bv,
    unsigned short* __restrict__ xb, float* __restrict__ bqkv,
    const float* __restrict__ Wq, const float* __restrict__ Wk,
    const float* __restrict__ Wv, const float* __restrict__ Wo,
    const float* __restrict__ F1, const float* __restrict__ F2,
    unsigned short* __restrict__ qkvT, unsigned short* __restrict__ WoT,
    unsigned short* __restrict__ F1T, unsigned short* __restrict__ F2T) {
  const int bid = blockIdx.x, tid = threadIdx.x;
  if (bid < 1024) {
    int gid = bid * 256 + tid;
    float4 v = ((const float4*)x)[gid];
    ushort4 s;
    s.x = f2bf(v.x); s.y = f2bf(v.y); s.z = f2bf(v.z); s.w = f2bf(v.w);
    ((ushort4*)xb)[gid] = s;
    if (gid < 1536)
      bqkv[gid] = gid < 512 ? bq[gid] : (gid < 1024 ? bk[gid - 512] : bv[gid - 1024]);
    return;
  }
  __shared__ float t[32][33];
  const int wid = bid - 1024;
  const float* src; unsigned short* dst; int R, C, tx, ty;
  if (wid < 1024) {
    int m = wid >> 8;
    src = m == 0 ? Wq : m == 1 ? Wk : m == 2 ? Wv : Wo;
    dst = m < 3 ? qkvT + m * 512 * 512 : WoT;
    R = 512; C = 512; int u = wid & 255; tx = u & 15; ty = u >> 4;
  } else if (wid < 2048) {
    src = F1; dst = F1T; R = 512; C = 2048;
    int u = wid - 1024; tx = u & 63; ty = u >> 6;
  } else {
    src = F2; dst = F2T; R = 2048; C = 512;
    int u = wid - 2048; tx = u & 15; ty = u >> 4;
  }
  int c0 = tx * 32, r0 = ty * 32;
  int x_ = tid & 31, y_ = tid >> 5;
#pragma unroll
  for (int i = 0; i < 4; i++)
    t[y_ + i * 8][x_] = src[(size_t)(r0 + y_ + i * 8) * C + c0 + x_];
  __syncthreads();
#pragma unroll
  for (int i = 0; i < 4; i++)
    dst[(size_t)(c0 + y_ + i * 8) * R + r0 + x_] = f2bf(t[x_][y_ + i * 8]);
}

// ---------------------------------------------------------------- GEMM ----
enum { EPI_F32 = 0, EPI_GELU = 1, EPI_QKV = 2 };

// device-side GEMM tile: counted-vmcnt 2-phase pipeline, swizzled LDS.
template <int EPI, int BMt, int BNt, int WM, int WN>
__device__ __forceinline__ void gemm_dev(
    char* smem, int bx, int by, int kz,
    const unsigned short* __restrict__ A, const unsigned short* __restrict__ Bt,
    const float* __restrict__ bias, void* __restrict__ O0, void* __restrict__ O1,
    void* __restrict__ O2, int M, int N, int K, int kb, int ksteps) {
  constexpr int Asz = BMt * 128;   // bytes per A buffer
  constexpr int Bsz = BNt * 128;
  char* Ab = smem;
  char* Bb = smem + 2 * Asz;
  const int tid = threadIdx.x, lane = tid & 63, w = tid >> 6;
  const int wr = w >> 1, wc = w & 1;
  const int m0 = by * BMt, n0 = bx * BNt;
  const int l15 = lane & 15, l4g = lane >> 4;
  constexpr int NL = BMt / 32 + BNt / 32;

  f32x4 acc[WM][WN];
#pragma unroll
  for (int i = 0; i < WM; i++)
#pragma unroll
    for (int j = 0; j < WN; j++) acc[i][j] = (f32x4){0.f, 0.f, 0.f, 0.f};

  auto stage = [&](int buf, int kt) {
#pragma unroll
    for (int it = 0; it < BMt / 32; ++it) {
      int c = it * 256 + tid, row = c >> 3;
      int s16 = (c & 7) ^ (row & 7);
      load_lds16(A + (size_t)(m0 + row) * K + kt * 64 + s16 * 8, Ab + buf * Asz + c * 16);
    }
#pragma unroll
    for (int it = 0; it < BNt / 32; ++it) {
      int c = it * 256 + tid, row = c >> 3;
      int s16 = (c & 7) ^ (row & 7);
      load_lds16(Bt + (size_t)(n0 + row) * K + kt * 64 + s16 * 8, Bb + buf * Bsz + c * 16);
    }
  };

  stage(0, kb);
  for (int ks = 0; ks < ksteps; ++ks) {
    const int cur = ks & 1;
    if (ks + 1 < ksteps) {
      stage(cur ^ 1, kb + ks + 1);
      if constexpr (NL == 6) WAITVM(6); else WAITVM(4);
    } else {
      WAITVM(0);
    }
    __builtin_amdgcn_s_barrier();
#pragma unroll
    for (int kk = 0; kk < 2; ++kk) {
      bf16x8 af[WM], bfv[WN];
#pragma unroll
      for (int i = 0; i < WM; i++) {
        int row = wr * (WM * 16) + i * 16 + l15;
        af[i] = *(const bf16x8*)(Ab + cur * Asz + row * 128 +
                                 (((kk * 4 + l4g) ^ (row & 7)) << 4));
      }
#pragma unroll
      for (int j = 0; j < WN; j++) {
        int row = wc * (WN * 16) + j * 16 + l15;
        bfv[j] = *(const bf16x8*)(Bb + cur * Bsz + row * 128 +
                                  (((kk * 4 + l4g) ^ (row & 7)) << 4));
      }
#pragma unroll
      for (int i = 0; i < WM; i++)
#pragma unroll
        for (int j = 0; j < WN; j++)
          acc[i][j] = __builtin_amdgcn_mfma_f32_16x16x32_bf16(af[i], bfv[j], acc[i][j], 0, 0, 0);
    }
    if (ks + 1 < ksteps) {
      asm volatile("" ::: "memory");
      __builtin_amdgcn_s_barrier();
    }
  }

#pragma unroll
  for (int i = 0; i < WM; i++) {
    int row = m0 + wr * (WM * 16) + i * 16 + l4g * 4;
#pragma unroll
    for (int j = 0; j < WN; j++) {
      int col = n0 + wc * (WN * 16) + j * 16 + l15;
      float bv = bias ? bias[col] : 0.f;
#pragma unroll
      for (int r = 0; r < 4; r++) {
        float v = acc[i][j][r] + bv;
        int rr = row + r;
        if (EPI == EPI_F32) {
          ((float*)O0)[(size_t)kz * M * N + (size_t)rr * N + col] = v;
        } else if (EPI == EPI_GELU) {
          ((unsigned short*)O0)[(size_t)rr * N + col] = f2bf(gelu_f(v));
        } else {  // QKV scatter
          int b = rr >> 10, n = rr & 1023;
          int d = col & 511, h = d >> 6, hd = d & 63;
          int bh = b * 8 + h;
          unsigned short bv16 = f2bf(v);
          if (col < 512)
            ((unsigned short*)O0)[((size_t)bh * 1024 + n) * 64 + hd] = bv16;
          else if (col < 1024)
            ((unsigned short*)O1)[((size_t)bh * 1024 + n) * 64 + hd] = bv16;
          else
            ((unsigned short*)O2)[((size_t)bh * 64 + hd) * 1024 + n] = bv16;
        }
      }
    }
  }
}

template <int EPI, int BMt, int BNt, int WM, int WN>
__global__ __launch_bounds__(256) void gemm_k(
    const unsigned short* __restrict__ A, const unsigned short* __restrict__ Bt,
    const float* __restrict__ bias, void* __restrict__ O0, void* __restrict__ O1,
    void* __restrict__ O2, int M, int N, int K, int ksteps) {
  __shared__ __align__(16) char pool[(BMt + BNt) * 256];
  gemm_dev<EPI, BMt, BNt, WM, WN>(pool, blockIdx.x, blockIdx.y, blockIdx.z,
                                  A, Bt, bias, O0, O1, O2, M, N, K,
                                  blockIdx.z * ksteps, ksteps);
}

// ---------------------------------------------------------------- RPE -----
// GEMM1 32x32x16 (K=4+bias); hidden via wave-private swizzled LDS (4KB/wave);
// GEMM2 16x16x32 with log2e pre-scaled R2/rb2; direct output stores.
__device__ __forceinline__ void rpe_dev(
    char* smem, int rbid,
    const float* __restrict__ rel, const float* __restrict__ R1,
    const float* __restrict__ rb1, const float* __restrict__ R2,
    const float* __restrict__ rb2, unsigned short* __restrict__ rpe) {
  const int tid = threadIdx.x, lane = tid & 63, w = tid >> 6;
  const int l31 = lane & 31, hi = lane >> 5;
  const int l15 = lane & 15, l4g = lane >> 4;
  const float LOG2E = 1.4426950408889634f;
  char* Hw = smem + w * 4096;

  bf16x8 a1[2];
#pragma unroll
  for (int mt = 0; mt < 2; mt++) {
    bf16x8 z = {};
    if (hi == 0) {
      int d = mt * 32 + l31;
      z[0] = (__bf16)R1[0 * 64 + d];
      z[1] = (__bf16)R1[1 * 64 + d];
      z[2] = (__bf16)R1[2 * 64 + d];
      z[3] = (__bf16)R1[3 * 64 + d];
      z[4] = (__bf16)rb1[d];
    }
    a1[mt] = z;
  }
  bf16x8 b2f[2];
#pragma unroll
  for (int ks = 0; ks < 2; ks++) {
    bf16x8 z = {};
    if (l15 < 8) {
#pragma unroll
      for (int j = 0; j < 8; j++)
        z[j] = (__bf16)(R2[(ks * 32 + l4g * 8 + j) * 8 + l15] * LOG2E);
    }
    b2f[ks] = z;
  }
  float rb2v = (l15 < 8) ? rb2[l15] * LOG2E : 0.f;

  const int wgid = rbid * 4 + w;                // 8192 waves
  float4 rv = {};
  if (hi == 0) rv = *(const float4*)&rel[(size_t)(wgid * 32 + l31) * 4];

  for (int c = 0; c < 8; c++) {
    int p0 = (wgid + c * 8192) * 32;
    float4 rc = rv;
    if (c < 7 && hi == 0)
      rv = *(const float4*)&rel[(size_t)((wgid + (c + 1) * 8192) * 32 + l31) * 4];

    bf16x8 b1 = {};
    if (hi == 0) {
      b1[0] = (__bf16)rc.x; b1[1] = (__bf16)rc.y;
      b1[2] = (__bf16)rc.z; b1[3] = (__bf16)rc.w;
      b1[4] = (__bf16)1.0f;
    }
    const int g1w = ((l31 & 7) ^ (l31 >> 3)) << 4;
#pragma unroll
    for (int mt = 0; mt < 2; mt++) {
      f32x16 hz = {};
      f32x16 h = __builtin_amdgcn_mfma_f32_32x32x16_bf16(a1[mt], b1, hz, 0, 0, 0);
#pragma unroll
      for (int q = 0; q < 4; q++) {
        float v0 = fmaxf(h[4 * q + 0], 0.f), v1 = fmaxf(h[4 * q + 1], 0.f);
        float v2 = fmaxf(h[4 * q + 2], 0.f), v3 = fmaxf(h[4 * q + 3], 0.f);
        uint2 pk; pk.x = pk2(v0, v1); pk.y = pk2(v2, v3);
        int byte = (l31 * 128 + mt * 64 + q * 16 + hi * 8) ^ g1w;
        *(uint2*)(Hw + byte) = pk;
      }
    }
    f32x4 acc2[2];
    acc2[0] = (f32x4){0.f, 0.f, 0.f, 0.f};
    acc2[1] = (f32x4){0.f, 0.f, 0.f, 0.f};
#pragma unroll
    for (int mt2 = 0; mt2 < 2; mt2++) {
      int row = mt2 * 16 + l15;
      int gr = ((row & 7) ^ (row >> 3)) << 4;
#pragma unroll
      for (int ks = 0; ks < 2; ks++) {
        int byte = row * 128 + (((ks * 4 + l4g) << 4) ^ gr);
        bf16x8 af = *(const bf16x8*)(Hw + byte);
        acc2[mt2] = __builtin_amdgcn_mfma_f32_16x16x32_bf16(af, b2f[ks], acc2[mt2], 0, 0, 0);
      }
    }
    if (l15 < 8) {
      int b = p0 >> 20, ij0 = (p0 & 1048575);
      size_t base = ((size_t)(b * 8 + l15) << 20) + ij0;
#pragma unroll
      for (int mt2 = 0; mt2 < 2; mt2++) {
        uint2 pk;
        pk.x = pk2(acc2[mt2][0] + rb2v, acc2[mt2][1] + rb2v);
        pk.y = pk2(acc2[mt2][2] + rb2v, acc2[mt2][3] + rb2v);
        *(uint2*)&rpe[base + mt2 * 16 + l4g * 4] = pk;
      }
    }
  }
}

// fused: blocks 0..383 QKV gemm (128x64), 384..2431 rpe. Shared 48KB pool.
__global__ __launch_bounds__(256) void rpe_qkv(
    const unsigned short* __restrict__ xb, const unsigned short* __restrict__ qkvT,
    const float* __restrict__ bqkv, unsigned short* __restrict__ Qhp,
    unsigned short* __restrict__ Khp, unsigned short* __restrict__ VTp,
    const float* __restrict__ rel, const float* __restrict__ R1,
    const float* __restrict__ rb1, const float* __restrict__ R2,
    const float* __restrict__ rb2, unsigned short* __restrict__ rpe) {
  __shared__ __align__(16) char pool[49152];
  const int bid = blockIdx.x;
  if (bid < 384)
    gemm_dev<EPI_QKV, 128, 64, 4, 2>(pool, bid % 24, bid / 24, 0,
                                     xb, qkvT, bqkv, Qhp, Khp, VTp,
                                     2048, 1536, 512, 0, 8);
  else
    rpe_dev(pool, bid - 384, rel, R1, rb1, R2, rb2, rpe);
}

// ------------------------------------------------------------- attention --
// swapped-operand QK/PV, no-max exp2 softmax, KV-split x2 + additive combine.
__global__ __launch_bounds__(256, 2) void attn_kernel(
    const unsigned short* __restrict__ Qh, const unsigned short* __restrict__ Kh,
    const unsigned short* __restrict__ VT, const unsigned short* __restrict__ rpe,
    float* __restrict__ oP, float* __restrict__ lP) {
  __shared__ unsigned short Ks[2][64 * 64], Vs[2][64 * 64], Rs[2][64 * 64];
  __shared__ unsigned short Ps[4][16 * 64];
  const int tid = threadIdx.x, lane = tid & 63, w = tid >> 6;
  const int l15 = lane & 15, l4g = lane >> 4;
  const int bid = blockIdx.x;
  const int it = (bid >> 3) & 15;
  const int bh = (bid & 7) | (((bid >> 7) & 1) << 3);
  const int kv = (bid >> 8) & 1;
  const int i0 = it * 64;
  const float C = 0.18033688011112042f;  // 0.125 * log2(e)
  const unsigned short* Qb = Qh + (size_t)bh * SEQ * HDIM;
  const unsigned short* Kb = Kh + (size_t)bh * SEQ * HDIM;
  const unsigned short* Vb = VT + (size_t)bh * HDIM * SEQ;
  const unsigned short* Rb = rpe + ((size_t)bh << 20);
  char* Pw = (char*)&Ps[w][0];

  bf16x8 qf[2];
#pragma unroll
  for (int kk = 0; kk < 2; kk++)
    qf[kk] = *(const bf16x8*)&Qb[(size_t)(i0 + w * 16 + l15) * 64 + kk * 32 + l4g * 8];

  f32x4 o[4];
#pragma unroll
  for (int i = 0; i < 4; i++) o[i] = (f32x4){0.f, 0.f, 0.f, 0.f};
  float lsum = 0.f;

  auto stage = [&](int buf, int jt) {
    int j0 = jt * 64;
#pragma unroll
    for (int itn = 0; itn < 2; ++itn) {
      int c = itn * 256 + tid, row = c >> 3;
      int s8 = ((c & 7) ^ (row & 7)) * 8;
      load_lds16(Kb + (size_t)(j0 + row) * 64 + s8, (char*)&Ks[buf][0] + c * 16);
      load_lds16(Vb + (size_t)row * SEQ + j0 + s8, (char*)&Vs[buf][0] + c * 16);
      load_lds16(Rb + (size_t)(i0 + row) * SEQ + j0 + s8, (char*)&Rs[buf][0] + c * 16);
    }
  };

  stage(0, kv * 8);
  for (int jtl = 0; jtl < 8; ++jtl) {
    const int cur = jtl & 1;
    if (jtl < 7) {
      stage(cur ^ 1, kv * 8 + jtl + 1);
      WAITVM(6);
    } else {
      WAITVM(0);
    }
    __builtin_amdgcn_s_barrier();

    f32x4 sa[4];
#pragma unroll
    for (int js = 0; js < 4; js++) sa[js] = (f32x4){0.f, 0.f, 0.f, 0.f};
    __builtin_amdgcn_s_setprio(1);
#pragma unroll
    for (int kk = 0; kk < 2; kk++) {
#pragma unroll
      for (int js = 0; js < 4; js++) {
        int row = js * 16 + l15;
        bf16x8 kb = *(const bf16x8*)((char*)&Ks[cur][0] + row * 128 +
                                     (((kk * 4 + l4g) ^ (row & 7)) << 4));
        sa[js] = __builtin_amdgcn_mfma_f32_16x16x32_bf16(kb, qf[kk], sa[js], 0, 0, 0);
      }
    }
    __builtin_amdgcn_s_setprio(0);

    const int rrow = w * 16 + l15;
    const int rswz = (rrow & 7) << 4;
    const int pswz = (l15 & 7) << 4;
#pragma unroll
    for (int js = 0; js < 4; js++) {
      int rbyte = rrow * 128 + ((((js * 2) + (l4g >> 1)) << 4) ^ rswz) + ((l4g & 1) << 3);
      uint2 rv2 = *(const uint2*)((const char*)&Rs[cur][0] + rbyte);
      float p0 = exp2f(sa[js][0] * C + bf2f((unsigned short)(rv2.x & 0xffff)));
      float p1 = exp2f(sa[js][1] * C + bf2f((unsigned short)(rv2.x >> 16)));
      float p2 = exp2f(sa[js][2] * C + bf2f((unsigned short)(rv2.y & 0xffff)));
      float p3 = exp2f(sa[js][3] * C + bf2f((unsigned short)(rv2.y >> 16)));
      lsum += (p0 + p1) + (p2 + p3);
      uint2 pk; pk.x = pk2(p0, p1); pk.y = pk2(p2, p3);
      *(uint2*)(Pw + l15 * 128 + (((js * 32 + l4g * 8)) ^ pswz)) = pk;
    }

    __builtin_amdgcn_s_setprio(1);
#pragma unroll
    for (int kk = 0; kk < 2; kk++) {
      bf16x8 pf = *(const bf16x8*)(Pw + l15 * 128 + ((kk * 64 + l4g * 16) ^ pswz));
#pragma unroll
      for (int hdf = 0; hdf < 4; hdf++) {
        int row = hdf * 16 + l15;
        bf16x8 vb = *(const bf16x8*)((char*)&Vs[cur][0] + row * 128 +
                                     (((kk * 4 + l4g) ^ (row & 7)) << 4));
        o[hdf] = __builtin_amdgcn_mfma_f32_16x16x32_bf16(vb, pf, o[hdf], 0, 0, 0);
      }
    }
    __builtin_amdgcn_s_setprio(0);
    if (jtl < 7) {
      asm volatile("" ::: "memory");
      __builtin_amdgcn_s_barrier();
    }
  }

  lsum += __shfl_xor(lsum, 16);
  lsum += __shfl_xor(lsum, 32);

  const int b = bh >> 3, h = bh & 7;
  const int nrow = b * SEQ + i0 + w * 16 + l15;
#pragma unroll
  for (int hdf = 0; hdf < 4; hdf++)
    *(f32x4*)&oP[(size_t)kv * 2048 * 512 + (size_t)nrow * 512 +
                 h * 64 + hdf * 16 + l4g * 4] = o[hdf];
  if (l4g == 0)
    lP[kv * 16384 + bh * 1024 + i0 + w * 16 + l15] = lsum;
}

__global__ __launch_bounds__(256) void attn_combine(
    const float* __restrict__ oP, const float* __restrict__ lP,
    unsigned short* __restrict__ AO) {
  const int n = blockIdx.x, t = threadIdx.x;
  float2 a = *(const float2*)&oP[(size_t)n * 512 + t * 2];
  float2 c = *(const float2*)&oP[(size_t)(2048 + n) * 512 + t * 2];
  int bh = (n >> 10) * 8 + (t >> 5), nq = n & 1023;
  float l = lP[bh * 1024 + nq] + lP[16384 + bh * 1024 + nq];
  float inv = 1.f / l;
  ((unsigned*)AO)[(size_t)n * 256 + t] = pk2((a.x + c.x) * inv, (a.y + c.y) * inv);
}

// ---------------------------------------------------------------- LN ------
// v = a + a2 + res (a2 = split-K partner partial), then layernorm.
__global__ __launch_bounds__(256) void ln_kernel(
    const float* __restrict__ a, const float* __restrict__ a2,
    const float* __restrict__ res, const float* __restrict__ g,
    const float* __restrict__ be, float* __restrict__ outf,
    unsigned short* __restrict__ outb) {
  const int row = blockIdx.x, t = threadIdx.x;
  const float* pa = a + (size_t)row * DMODEL;
  const float* pc = a2 + (size_t)row * DMODEL;
  const float* pb = res + (size_t)row * DMODEL;
  float v0 = pa[t] + pc[t] + pb[t];
  float v1 = pa[t + 256] + pc[t + 256] + pb[t + 256];
  float s = v0 + v1, sq = v0 * v0 + v1 * v1;
#pragma unroll
  for (int off = 1; off < 64; off <<= 1) {
    s += __shfl_xor(s, off);
    sq += __shfl_xor(sq, off);
  }
  __shared__ float ls[4], lq[4];
  int w = t >> 6, lane = t & 63;
  if (lane == 0) { ls[w] = s; lq[w] = sq; }
  __syncthreads();
  s = ls[0] + ls[1] + ls[2] + ls[3];
  sq = lq[0] + lq[1] + lq[2] + lq[3];
  float mu = s * (1.f / DMODEL);
  float var = sq * (1.f / DMODEL) - mu * mu;
  float rs = rsqrtf(var + 1e-5f);
  float y0 = (v0 - mu) * rs * g[t] + be[t];
  float y1v = (v1 - mu) * rs * g[t + 256] + be[t + 256];
  outf[(size_t)row * DMODEL + t] = y0;
  outf[(size_t)row * DMODEL + t + 256] = y1v;
  if (outb) {
    outb[(size_t)row * DMODEL + t] = f2bf(y0);
    outb[(size_t)row * DMODEL + t + 256] = f2bf(y1v);
  }
}

// ---------------------------------------------------------------- launch --
extern "C" void kernel_launch(void* const* d_in, const int* in_sizes, int n_in,
                              void* d_out, int out_size, void* d_ws, size_t ws_size,
                              hipStream_t stream) {
  const float* x   = (const float*)d_in[0];
  const float* rel = (const float*)d_in[1];
  const float* Wq  = (const float*)d_in[2];
  const float* bq  = (const float*)d_in[3];
  const float* Wk  = (const float*)d_in[4];
  const float* bk  = (const float*)d_in[5];
  const float* Wv  = (const float*)d_in[6];
  const float* bv  = (const float*)d_in[7];
  const float* Wo  = (const float*)d_in[8];
  const float* bo  = (const float*)d_in[9];
  const float* R1  = (const float*)d_in[10];
  const float* rb1 = (const float*)d_in[11];
  const float* R2  = (const float*)d_in[12];
  const float* rb2 = (const float*)d_in[13];
  const float* g1  = (const float*)d_in[14];
  const float* b1  = (const float*)d_in[15];
  const float* g2  = (const float*)d_in[16];
  const float* b2  = (const float*)d_in[17];
  const float* F1  = (const float*)d_in[18];
  const float* fb1 = (const float*)d_in[19];
  const float* F2  = (const float*)d_in[20];
  const float* fb2 = (const float*)d_in[21];

  char* p = (char*)d_ws;
  auto alloc = [&](size_t bytes) {
    char* r = p;
    p += (bytes + 255) & ~(size_t)255;
    return r;
  };
  unsigned short* xb   = (unsigned short*)alloc((size_t)2048 * 512 * 2);
  unsigned short* qkvT = (unsigned short*)alloc((size_t)1536 * 512 * 2);
  float*          bqkv = (float*)alloc(1536 * 4);
  unsigned short* WoT  = (unsigned short*)alloc((size_t)512 * 512 * 2);
  unsigned short* F1T  = (unsigned short*)alloc((size_t)2048 * 512 * 2);
  unsigned short* F2T  = (unsigned short*)alloc((size_t)512 * 2048 * 2);
  unsigned short* Qhp  = (unsigned short*)alloc((size_t)BH * SEQ * HDIM * 2);
  unsigned short* Khp  = (unsigned short*)alloc((size_t)BH * SEQ * HDIM * 2);
  unsigned short* VTp  = (unsigned short*)alloc((size_t)BH * HDIM * SEQ * 2);
  unsigned short* rpep = (unsigned short*)alloc((size_t)BH * SEQ * SEQ * 2);   // 32MB
  unsigned short* attO = (unsigned short*)alloc((size_t)2048 * 512 * 2);
  float*          t1x  = (float*)alloc((size_t)2 * 2048 * 512 * 4);   // 16MB partials
  float*          y1   = (float*)alloc((size_t)2048 * 512 * 4);
  unsigned short* y1b  = (unsigned short*)alloc((size_t)2048 * 512 * 2);
  unsigned short* hbuf = rpep;                   // rpe dead after attention
  float*          oP   = t1x;                    // 8MB used during attn
  float*          lP   = (float*)y1b;            // y1b free during attn

  prep_all<<<4096, 256, 0, stream>>>(x, bq, bk, bv, xb, bqkv,
                                     Wq, Wk, Wv, Wo, F1, F2, qkvT, WoT, F1T, F2T);
  // fused rpe + QKV projection (384 gemm blocks + 2048 rpe blocks)
  rpe_qkv<<<2432, 256, 0, stream>>>(xb, qkvT, bqkv, Qhp, Khp, VTp,
                                    rel, R1, rb1, R2, rb2, rpep);
  attn_kernel<<<512, 256, 0, stream>>>(Qhp, Khp, VTp, rpep, oP, lP);
  attn_combine<<<2048, 256, 0, stream>>>(oP, lP, attO);

  // Wo: split-K x2 -> t1x partials (grid 512)
  gemm_k<EPI_F32, 64, 64, 2, 2><<<dim3(8, 32, 2), 256, 0, stream>>>(
      attO, WoT, bo, t1x, nullptr, nullptr, 2048, 512, 512, 4);
  ln_kernel<<<2048, 256, 0, stream>>>(t1x, t1x + (size_t)2048 * 512, x,
                                      g1, b1, y1, y1b);

  // FFN1: 64x64 tiles -> 1024 blocks
  gemm_k<EPI_GELU, 64, 64, 2, 2><<<dim3(32, 32, 1), 256, 0, stream>>>(
      y1b, F1T, fb1, hbuf, nullptr, nullptr, 2048, 2048, 512, 8);
  // FFN2: split-K x2 -> t1x partials (grid 512)
  gemm_k<EPI_F32, 64, 64, 2, 2><<<dim3(8, 32, 2), 256, 0, stream>>>(
      hbuf, F2T, fb2, t1x, nullptr, nullptr, 2048, 512, 2048, 16);
  ln_kernel<<<2048, 256, 0, stream>>>(t1x, t1x + (size_t)2048 * 512, y1,
                                      g2, b2, (float*)d_out, nullptr);
}

// Round 10
// 213.199 us; speedup vs baseline: 1.1650x; 1.0258x over previous
//
#include <hip/hip_runtime.h>
#include <math.h>

// Problem constants
#define BATCH 2
#define SEQ   1024
#define DMODEL 512
#define NHEAD 8
#define HDIM  64
#define FFND  2048
#define BH    (BATCH*NHEAD)   // 16

typedef float  f32x4   __attribute__((ext_vector_type(4)));
typedef float  f32x16  __attribute__((ext_vector_type(16)));
typedef __bf16 bf16x8  __attribute__((ext_vector_type(8)));

#define WAITVM(n) asm volatile("s_waitcnt vmcnt(" #n ")" ::: "memory")

__device__ __forceinline__ unsigned short f2bf(float f) {
  union { __bf16 h; unsigned short u; } z; z.h = (__bf16)f; return z.u;
}
__device__ __forceinline__ float bf2f(unsigned short h) {
  union { unsigned u; float f; } x; x.u = ((unsigned)h) << 16;
  return x.f;
}
__device__ __forceinline__ unsigned pk2(float a, float b) {
  union { __bf16 h[2]; unsigned u; } z;
  z.h[0] = (__bf16)a; z.h[1] = (__bf16)b; return z.u;
}
__device__ __forceinline__ float gelu_f(float v) {
  float u = 0.7978845608f * (v + 0.044715f * v * v * v);
  float a = fabsf(u);
  float e = __expf(-2.f * a);
  float t = (1.f - e) / (1.f + e);
  t = copysignf(t, u);
  return 0.5f * v * (1.f + t);
}

__device__ __forceinline__ void load_lds16(const void* g, void* l) {
  __builtin_amdgcn_global_load_lds((const __attribute__((address_space(1))) void*)g,
                                   (__attribute__((address_space(3))) void*)l, 16, 0, 0);
}

// ---------------------------------------------------------------- prep ----
// bid<1024: x->bf16 cast (+bias pack). bid>=1024: weight transpose-casts.
__global__ __launch_bounds__(256) void prep_all(
    const float* __restrict__ x, const float* __restrict__ bq,
    const float* __restrict__ bk, const float* __restrict__ bv,
    unsigned short* __restrict__ xb, float* __restrict__ bqkv,
    const float* __restrict__ Wq, const float* __restrict__ Wk,
    const float* __restrict__ Wv, const float* __restrict__ Wo,
    const float* __restrict__ F1, const float* __restrict__ F2,
    unsigned short* __restrict__ qkvT, unsigned short* __restrict__ WoT,
    unsigned short* __restrict__ F1T, unsigned short* __restrict__ F2T) {
  const int bid = blockIdx.x, tid = threadIdx.x;
  if (bid < 1024) {
    int gid = bid * 256 + tid;
    float4 v = ((const float4*)x)[gid];
    ushort4 s;
    s.x = f2bf(v.x); s.y = f2bf(v.y); s.z = f2bf(v.z); s.w = f2bf(v.w);
    ((ushort4*)xb)[gid] = s;
    if (gid < 1536)
      bqkv[gid] = gid < 512 ? bq[gid] : (gid < 1024 ? bk[gid - 512] : bv[gid - 1024]);
    return;
  }
  __shared__ float t[32][33];
  const int wid = bid - 1024;
  const float* src; unsigned short* dst; int R, C, tx, ty;
  if (wid < 1024) {
    int m = wid >> 8;
    src = m == 0 ? Wq : m == 1 ? Wk : m == 2 ? Wv : Wo;
    dst = m < 3 ? qkvT + m * 512 * 512 : WoT;
    R = 512; C = 512; int u = wid & 255; tx = u & 15; ty = u >> 4;
  } else if (wid < 2048) {
    src = F1; dst = F1T; R = 512; C = 2048;
    int u = wid - 1024; tx = u & 63; ty = u >> 6;
  } else {
    src = F2; dst = F2T; R = 2048; C = 512;
    int u = wid - 2048; tx = u & 15; ty = u >> 4;
  }
  int c0 = tx * 32, r0 = ty * 32;
  int x_ = tid & 31, y_ = tid >> 5;
#pragma unroll
  for (int i = 0; i < 4; i++)
    t[y_ + i * 8][x_] = src[(size_t)(r0 + y_ + i * 8) * C + c0 + x_];
  __syncthreads();
#pragma unroll
  for (int i = 0; i < 4; i++)
    dst[(size_t)(c0 + y_ + i * 8) * R + r0 + x_] = f2bf(t[x_][y_ + i * 8]);
}

// ---------------------------------------------------------------- GEMM ----
enum { EPI_F32 = 0, EPI_GELU = 1, EPI_QKV = 2 };

// device-side GEMM tile: counted-vmcnt 2-phase pipeline, swizzled LDS.
template <int EPI, int BMt, int BNt, int WM, int WN>
__device__ __forceinline__ void gemm_dev(
    char* smem, int bx, int by, int kz,
    const unsigned short* __restrict__ A, const unsigned short* __restrict__ Bt,
    const float* __restrict__ bias, void* __restrict__ O0, void* __restrict__ O1,
    void* __restrict__ O2, int M, int N, int K, int kb, int ksteps) {
  constexpr int Asz = BMt * 128;   // bytes per A buffer
  constexpr int Bsz = BNt * 128;
  char* Ab = smem;
  char* Bb = smem + 2 * Asz;
  const int tid = threadIdx.x, lane = tid & 63, w = tid >> 6;
  const int wr = w >> 1, wc = w & 1;
  const int m0 = by * BMt, n0 = bx * BNt;
  const int l15 = lane & 15, l4g = lane >> 4;
  constexpr int NL = BMt / 32 + BNt / 32;

  f32x4 acc[WM][WN];
#pragma unroll
  for (int i = 0; i < WM; i++)
#pragma unroll
    for (int j = 0; j < WN; j++) acc[i][j] = (f32x4){0.f, 0.f, 0.f, 0.f};

  auto stage = [&](int buf, int kt) {
#pragma unroll
    for (int it = 0; it < BMt / 32; ++it) {
      int c = it * 256 + tid, row = c >> 3;
      int s16 = (c & 7) ^ (row & 7);
      load_lds16(A + (size_t)(m0 + row) * K + kt * 64 + s16 * 8, Ab + buf * Asz + c * 16);
    }
#pragma unroll
    for (int it = 0; it < BNt / 32; ++it) {
      int c = it * 256 + tid, row = c >> 3;
      int s16 = (c & 7) ^ (row & 7);
      load_lds16(Bt + (size_t)(n0 + row) * K + kt * 64 + s16 * 8, Bb + buf * Bsz + c * 16);
    }
  };

  stage(0, kb);
  for (int ks = 0; ks < ksteps; ++ks) {
    const int cur = ks & 1;
    if (ks + 1 < ksteps) {
      stage(cur ^ 1, kb + ks + 1);
      if constexpr (NL == 6) WAITVM(6); else WAITVM(4);
    } else {
      WAITVM(0);
    }
    __builtin_amdgcn_s_barrier();
#pragma unroll
    for (int kk = 0; kk < 2; ++kk) {
      bf16x8 af[WM], bfv[WN];
#pragma unroll
      for (int i = 0; i < WM; i++) {
        int row = wr * (WM * 16) + i * 16 + l15;
        af[i] = *(const bf16x8*)(Ab + cur * Asz + row * 128 +
                                 (((kk * 4 + l4g) ^ (row & 7)) << 4));
      }
#pragma unroll
      for (int j = 0; j < WN; j++) {
        int row = wc * (WN * 16) + j * 16 + l15;
        bfv[j] = *(const bf16x8*)(Bb + cur * Bsz + row * 128 +
                                  (((kk * 4 + l4g) ^ (row & 7)) << 4));
      }
#pragma unroll
      for (int i = 0; i < WM; i++)
#pragma unroll
        for (int j = 0; j < WN; j++)
          acc[i][j] = __builtin_amdgcn_mfma_f32_16x16x32_bf16(af[i], bfv[j], acc[i][j], 0, 0, 0);
    }
    if (ks + 1 < ksteps) {
      asm volatile("" ::: "memory");
      __builtin_amdgcn_s_barrier();
    }
  }

#pragma unroll
  for (int i = 0; i < WM; i++) {
    int row = m0 + wr * (WM * 16) + i * 16 + l4g * 4;
#pragma unroll
    for (int j = 0; j < WN; j++) {
      int col = n0 + wc * (WN * 16) + j * 16 + l15;
      float bv = bias ? bias[col] : 0.f;
#pragma unroll
      for (int r = 0; r < 4; r++) {
        float v = acc[i][j][r] + bv;
        int rr = row + r;
        if (EPI == EPI_F32) {
          ((float*)O0)[(size_t)kz * M * N + (size_t)rr * N + col] = v;
        } else if (EPI == EPI_GELU) {
          ((unsigned short*)O0)[(size_t)rr * N + col] = f2bf(gelu_f(v));
        } else {  // QKV scatter
          int b = rr >> 10, n = rr & 1023;
          int d = col & 511, h = d >> 6, hd = d & 63;
          int bh = b * 8 + h;
          unsigned short bv16 = f2bf(v);
          if (col < 512)
            ((unsigned short*)O0)[((size_t)bh * 1024 + n) * 64 + hd] = bv16;
          else if (col < 1024)
            ((unsigned short*)O1)[((size_t)bh * 1024 + n) * 64 + hd] = bv16;
          else
            ((unsigned short*)O2)[((size_t)bh * 64 + hd) * 1024 + n] = bv16;
        }
      }
    }
  }
}

template <int EPI, int BMt, int BNt, int WM, int WN>
__global__ __launch_bounds__(256) void gemm_k(
    const unsigned short* __restrict__ A, const unsigned short* __restrict__ Bt,
    const float* __restrict__ bias, void* __restrict__ O0, void* __restrict__ O1,
    void* __restrict__ O2, int M, int N, int K, int ksteps) {
  __shared__ __align__(16) char pool[(BMt + BNt) * 256];
  gemm_dev<EPI, BMt, BNt, WM, WN>(pool, blockIdx.x, blockIdx.y, blockIdx.z,
                                  A, Bt, bias, O0, O1, O2, M, N, K,
                                  blockIdx.z * ksteps, ksteps);
}

// ---------------------------------------------------------------- RPE -----
// v5: chunk-pipelined. Double-buffered wave-private H (2x4KB); GEMM2 of
// chunk c-1 overlaps GEMM1 of chunk c (kills same-iter write->read wait).
__device__ __forceinline__ void rpe_dev(
    char* smem, int rbid,
    const float* __restrict__ rel, const float* __restrict__ R1,
    const float* __restrict__ rb1, const float* __restrict__ R2,
    const float* __restrict__ rb2, unsigned short* __restrict__ rpe) {
  const int tid = threadIdx.x, lane = tid & 63, w = tid >> 6;
  const int l31 = lane & 31, hi = lane >> 5;
  const int l15 = lane & 15, l4g = lane >> 4;
  const float LOG2E = 1.4426950408889634f;
  char* Hw = smem + w * 8192;   // 2 buffers x 4096B

  bf16x8 a1[2];
#pragma unroll
  for (int mt = 0; mt < 2; mt++) {
    bf16x8 z = {};
    if (hi == 0) {
      int d = mt * 32 + l31;
      z[0] = (__bf16)R1[0 * 64 + d];
      z[1] = (__bf16)R1[1 * 64 + d];
      z[2] = (__bf16)R1[2 * 64 + d];
      z[3] = (__bf16)R1[3 * 64 + d];
      z[4] = (__bf16)rb1[d];
    }
    a1[mt] = z;
  }
  bf16x8 b2f[2];
#pragma unroll
  for (int ks = 0; ks < 2; ks++) {
    bf16x8 z = {};
    if (l15 < 8) {
#pragma unroll
      for (int j = 0; j < 8; j++)
        z[j] = (__bf16)(R2[(ks * 32 + l4g * 8 + j) * 8 + l15] * LOG2E);
    }
    b2f[ks] = z;
  }
  float rb2v = (l15 < 8) ? rb2[l15] * LOG2E : 0.f;

  const int wgid = rbid * 4 + w;                // 8192 waves
  const int g1w = ((l31 & 7) ^ (l31 >> 3)) << 4;

  auto gemm1 = [&](const float4& rc, int buf) {
    bf16x8 b1 = {};
    if (hi == 0) {
      b1[0] = (__bf16)rc.x; b1[1] = (__bf16)rc.y;
      b1[2] = (__bf16)rc.z; b1[3] = (__bf16)rc.w;
      b1[4] = (__bf16)1.0f;
    }
#pragma unroll
    for (int mt = 0; mt < 2; mt++) {
      f32x16 hz = {};
      f32x16 h = __builtin_amdgcn_mfma_f32_32x32x16_bf16(a1[mt], b1, hz, 0, 0, 0);
#pragma unroll
      for (int q = 0; q < 4; q++) {
        float v0 = fmaxf(h[4 * q + 0], 0.f), v1 = fmaxf(h[4 * q + 1], 0.f);
        float v2 = fmaxf(h[4 * q + 2], 0.f), v3 = fmaxf(h[4 * q + 3], 0.f);
        uint2 pk; pk.x = pk2(v0, v1); pk.y = pk2(v2, v3);
        int byte = (l31 * 128 + mt * 64 + q * 16 + hi * 8) ^ g1w;
        *(uint2*)(Hw + buf * 4096 + byte) = pk;
      }
    }
  };
  auto gemm2_store = [&](int p0, int buf) {
    f32x4 acc2[2];
    acc2[0] = (f32x4){0.f, 0.f, 0.f, 0.f};
    acc2[1] = (f32x4){0.f, 0.f, 0.f, 0.f};
#pragma unroll
    for (int mt2 = 0; mt2 < 2; mt2++) {
      int row = mt2 * 16 + l15;
      int gr = ((row & 7) ^ (row >> 3)) << 4;
#pragma unroll
      for (int ks = 0; ks < 2; ks++) {
        int byte = row * 128 + (((ks * 4 + l4g) << 4) ^ gr);
        bf16x8 af = *(const bf16x8*)(Hw + buf * 4096 + byte);
        acc2[mt2] = __builtin_amdgcn_mfma_f32_16x16x32_bf16(af, b2f[ks], acc2[mt2], 0, 0, 0);
      }
    }
    if (l15 < 8) {
      int b = p0 >> 20, ij0 = (p0 & 1048575);
      size_t base = ((size_t)(b * 8 + l15) << 20) + ij0;
#pragma unroll
      for (int mt2 = 0; mt2 < 2; mt2++) {
        uint2 pk;
        pk.x = pk2(acc2[mt2][0] + rb2v, acc2[mt2][1] + rb2v);
        pk.y = pk2(acc2[mt2][2] + rb2v, acc2[mt2][3] + rb2v);
        *(uint2*)&rpe[base + mt2 * 16 + l4g * 4] = pk;
      }
    }
  };

  float4 rv = {};
  if (hi == 0) rv = *(const float4*)&rel[(size_t)(wgid * 32 + l31) * 4];
  int p0_prev = 0;
  for (int c = 0; c < 8; c++) {
    int p0 = (wgid + c * 8192) * 32;
    float4 rc = rv;
    if (c < 7 && hi == 0)
      rv = *(const float4*)&rel[(size_t)((wgid + (c + 1) * 8192) * 32 + l31) * 4];
    gemm1(rc, c & 1);
    if (c > 0) gemm2_store(p0_prev, (c & 1) ^ 1);
    p0_prev = p0;
  }
  gemm2_store(p0_prev, 1);
}

// fused: blocks 0..767 QKV gemm (64x64), 768..2815 rpe. Shared 32KB pool
// -> 5 blocks/CU.
__global__ __launch_bounds__(256) void rpe_qkv(
    const unsigned short* __restrict__ xb, const unsigned short* __restrict__ qkvT,
    const float* __restrict__ bqkv, unsigned short* __restrict__ Qhp,
    unsigned short* __restrict__ Khp, unsigned short* __restrict__ VTp,
    const float* __restrict__ rel, const float* __restrict__ R1,
    const float* __restrict__ rb1, const float* __restrict__ R2,
    const float* __restrict__ rb2, unsigned short* __restrict__ rpe) {
  __shared__ __align__(16) char pool[32768];
  const int bid = blockIdx.x;
  if (bid < 768)
    gemm_dev<EPI_QKV, 64, 64, 2, 2>(pool, bid % 24, bid / 24, 0,
                                    xb, qkvT, bqkv, Qhp, Khp, VTp,
                                    2048, 1536, 512, 0, 8);
  else
    rpe_dev(pool, bid - 768, rel, R1, rb1, R2, rb2, rpe);
}

// ------------------------------------------------------------- attention --
// swapped-operand QK/PV, no-max exp2 softmax, KV-split x2 + additive combine.
__global__ __launch_bounds__(256, 2) void attn_kernel(
    const unsigned short* __restrict__ Qh, const unsigned short* __restrict__ Kh,
    const unsigned short* __restrict__ VT, const unsigned short* __restrict__ rpe,
    float* __restrict__ oP, float* __restrict__ lP) {
  __shared__ unsigned short Ks[2][64 * 64], Vs[2][64 * 64], Rs[2][64 * 64];
  __shared__ unsigned short Ps[4][16 * 64];
  const int tid = threadIdx.x, lane = tid & 63, w = tid >> 6;
  const int l15 = lane & 15, l4g = lane >> 4;
  const int bid = blockIdx.x;
  const int it = (bid >> 3) & 15;
  const int bh = (bid & 7) | (((bid >> 7) & 1) << 3);
  const int kv = (bid >> 8) & 1;
  const int i0 = it * 64;
  const float C = 0.18033688011112042f;  // 0.125 * log2(e)
  const unsigned short* Qb = Qh + (size_t)bh * SEQ * HDIM;
  const unsigned short* Kb = Kh + (size_t)bh * SEQ * HDIM;
  const unsigned short* Vb = VT + (size_t)bh * HDIM * SEQ;
  const unsigned short* Rb = rpe + ((size_t)bh << 20);
  char* Pw = (char*)&Ps[w][0];

  bf16x8 qf[2];
#pragma unroll
  for (int kk = 0; kk < 2; kk++)
    qf[kk] = *(const bf16x8*)&Qb[(size_t)(i0 + w * 16 + l15) * 64 + kk * 32 + l4g * 8];

  f32x4 o[4];
#pragma unroll
  for (int i = 0; i < 4; i++) o[i] = (f32x4){0.f, 0.f, 0.f, 0.f};
  float lsum = 0.f;

  auto stage = [&](int buf, int jt) {
    int j0 = jt * 64;
#pragma unroll
    for (int itn = 0; itn < 2; ++itn) {
      int c = itn * 256 + tid, row = c >> 3;
      int s8 = ((c & 7) ^ (row & 7)) * 8;
      load_lds16(Kb + (size_t)(j0 + row) * 64 + s8, (char*)&Ks[buf][0] + c * 16);
      load_lds16(Vb + (size_t)row * SEQ + j0 + s8, (char*)&Vs[buf][0] + c * 16);
      load_lds16(Rb + (size_t)(i0 + row) * SEQ + j0 + s8, (char*)&Rs[buf][0] + c * 16);
    }
  };

  stage(0, kv * 8);
  for (int jtl = 0; jtl < 8; ++jtl) {
    const int cur = jtl & 1;
    if (jtl < 7) {
      stage(cur ^ 1, kv * 8 + jtl + 1);
      WAITVM(6);
    } else {
      WAITVM(0);
    }
    __builtin_amdgcn_s_barrier();

    f32x4 sa[4];
#pragma unroll
    for (int js = 0; js < 4; js++) sa[js] = (f32x4){0.f, 0.f, 0.f, 0.f};
    __builtin_amdgcn_s_setprio(1);
#pragma unroll
    for (int kk = 0; kk < 2; kk++) {
#pragma unroll
      for (int js = 0; js < 4; js++) {
        int row = js * 16 + l15;
        bf16x8 kb = *(const bf16x8*)((char*)&Ks[cur][0] + row * 128 +
                                     (((kk * 4 + l4g) ^ (row & 7)) << 4));
        sa[js] = __builtin_amdgcn_mfma_f32_16x16x32_bf16(kb, qf[kk], sa[js], 0, 0, 0);
      }
    }
    __builtin_amdgcn_s_setprio(0);

    const int rrow = w * 16 + l15;
    const int rswz = (rrow & 7) << 4;
    const int pswz = (l15 & 7) << 4;
#pragma unroll
    for (int js = 0; js < 4; js++) {
      int rbyte = rrow * 128 + ((((js * 2) + (l4g >> 1)) << 4) ^ rswz) + ((l4g & 1) << 3);
      uint2 rv2 = *(const uint2*)((const char*)&Rs[cur][0] + rbyte);
      float p0 = exp2f(sa[js][0] * C + bf2f((unsigned short)(rv2.x & 0xffff)));
      float p1 = exp2f(sa[js][1] * C + bf2f((unsigned short)(rv2.x >> 16)));
      float p2 = exp2f(sa[js][2] * C + bf2f((unsigned short)(rv2.y & 0xffff)));
      float p3 = exp2f(sa[js][3] * C + bf2f((unsigned short)(rv2.y >> 16)));
      lsum += (p0 + p1) + (p2 + p3);
      uint2 pk; pk.x = pk2(p0, p1); pk.y = pk2(p2, p3);
      *(uint2*)(Pw + l15 * 128 + (((js * 32 + l4g * 8)) ^ pswz)) = pk;
    }

    __builtin_amdgcn_s_setprio(1);
#pragma unroll
    for (int kk = 0; kk < 2; kk++) {
      bf16x8 pf = *(const bf16x8*)(Pw + l15 * 128 + ((kk * 64 + l4g * 16) ^ pswz));
#pragma unroll
      for (int hdf = 0; hdf < 4; hdf++) {
        int row = hdf * 16 + l15;
        bf16x8 vb = *(const bf16x8*)((char*)&Vs[cur][0] + row * 128 +
                                     (((kk * 4 + l4g) ^ (row & 7)) << 4));
        o[hdf] = __builtin_amdgcn_mfma_f32_16x16x32_bf16(vb, pf, o[hdf], 0, 0, 0);
      }
    }
    __builtin_amdgcn_s_setprio(0);
    if (jtl < 7) {
      asm volatile("" ::: "memory");
      __builtin_amdgcn_s_barrier();
    }
  }

  lsum += __shfl_xor(lsum, 16);
  lsum += __shfl_xor(lsum, 32);

  const int b = bh >> 3, h = bh & 7;
  const int nrow = b * SEQ + i0 + w * 16 + l15;
#pragma unroll
  for (int hdf = 0; hdf < 4; hdf++)
    *(f32x4*)&oP[(size_t)kv * 2048 * 512 + (size_t)nrow * 512 +
                 h * 64 + hdf * 16 + l4g * 4] = o[hdf];
  if (l4g == 0)
    lP[kv * 16384 + bh * 1024 + i0 + w * 16 + l15] = lsum;
}

__global__ __launch_bounds__(256) void attn_combine(
    const float* __restrict__ oP, const float* __restrict__ lP,
    unsigned short* __restrict__ AO) {
  const int n = blockIdx.x, t = threadIdx.x;
  float2 a = *(const float2*)&oP[(size_t)n * 512 + t * 2];
  float2 c = *(const float2*)&oP[(size_t)(2048 + n) * 512 + t * 2];
  int bh = (n >> 10) * 8 + (t >> 5), nq = n & 1023;
  float l = lP[bh * 1024 + nq] + lP[16384 + bh * 1024 + nq];
  float inv = 1.f / l;
  ((unsigned*)AO)[(size_t)n * 256 + t] = pk2((a.x + c.x) * inv, (a.y + c.y) * inv);
}

// ---------------------------------------------------------------- LN ------
// v = a + a2 + res (a2 = split-K partner partial), then layernorm.
__global__ __launch_bounds__(256) void ln_kernel(
    const float* __restrict__ a, const float* __restrict__ a2,
    const float* __restrict__ res, const float* __restrict__ g,
    const float* __restrict__ be, float* __restrict__ outf,
    unsigned short* __restrict__ outb) {
  const int row = blockIdx.x, t = threadIdx.x;
  const float* pa = a + (size_t)row * DMODEL;
  const float* pc = a2 + (size_t)row * DMODEL;
  const float* pb = res + (size_t)row * DMODEL;
  float v0 = pa[t] + pc[t] + pb[t];
  float v1 = pa[t + 256] + pc[t + 256] + pb[t + 256];
  float s = v0 + v1, sq = v0 * v0 + v1 * v1;
#pragma unroll
  for (int off = 1; off < 64; off <<= 1) {
    s += __shfl_xor(s, off);
    sq += __shfl_xor(sq, off);
  }
  __shared__ float ls[4], lq[4];
  int w = t >> 6, lane = t & 63;
  if (lane == 0) { ls[w] = s; lq[w] = sq; }
  __syncthreads();
  s = ls[0] + ls[1] + ls[2] + ls[3];
  sq = lq[0] + lq[1] + lq[2] + lq[3];
  float mu = s * (1.f / DMODEL);
  float var = sq * (1.f / DMODEL) - mu * mu;
  float rs = rsqrtf(var + 1e-5f);
  float y0 = (v0 - mu) * rs * g[t] + be[t];
  float y1v = (v1 - mu) * rs * g[t + 256] + be[t + 256];
  outf[(size_t)row * DMODEL + t] = y0;
  outf[(size_t)row * DMODEL + t + 256] = y1v;
  if (outb) {
    outb[(size_t)row * DMODEL + t] = f2bf(y0);
    outb[(size_t)row * DMODEL + t + 256] = f2bf(y1v);
  }
}

// ---------------------------------------------------------------- launch --
extern "C" void kernel_launch(void* const* d_in, const int* in_sizes, int n_in,
                              void* d_out, int out_size, void* d_ws, size_t ws_size,
                              hipStream_t stream) {
  const float* x   = (const float*)d_in[0];
  const float* rel = (const float*)d_in[1];
  const float* Wq  = (const float*)d_in[2];
  const float* bq  = (const float*)d_in[3];
  const float* Wk  = (const float*)d_in[4];
  const float* bk  = (const float*)d_in[5];
  const float* Wv  = (const float*)d_in[6];
  const float* bv  = (const float*)d_in[7];
  const float* Wo  = (const float*)d_in[8];
  const float* bo  = (const float*)d_in[9];
  const float* R1  = (const float*)d_in[10];
  const float* rb1 = (const float*)d_in[11];
  const float* R2  = (const float*)d_in[12];
  const float* rb2 = (const float*)d_in[13];
  const float* g1  = (const float*)d_in[14];
  const float* b1  = (const float*)d_in[15];
  const float* g2  = (const float*)d_in[16];
  const float* b2  = (const float*)d_in[17];
  const float* F1  = (const float*)d_in[18];
  const float* fb1 = (const float*)d_in[19];
  const float* F2  = (const float*)d_in[20];
  const float* fb2 = (const float*)d_in[21];

  char* p = (char*)d_ws;
  auto alloc = [&](size_t bytes) {
    char* r = p;
    p += (bytes + 255) & ~(size_t)255;
    return r;
  };
  unsigned short* xb   = (unsigned short*)alloc((size_t)2048 * 512 * 2);
  unsigned short* qkvT = (unsigned short*)alloc((size_t)1536 * 512 * 2);
  float*          bqkv = (float*)alloc(1536 * 4);
  unsigned short* WoT  = (unsigned short*)alloc((size_t)512 * 512 * 2);
  unsigned short* F1T  = (unsigned short*)alloc((size_t)2048 * 512 * 2);
  unsigned short* F2T  = (unsigned short*)alloc((size_t)512 * 2048 * 2);
  unsigned short* Qhp  = (unsigned short*)alloc((size_t)BH * SEQ * HDIM * 2);
  unsigned short* Khp  = (unsigned short*)alloc((size_t)BH * SEQ * HDIM * 2);
  unsigned short* VTp  = (unsigned short*)alloc((size_t)BH * HDIM * SEQ * 2);
  unsigned short* rpep = (unsigned short*)alloc((size_t)BH * SEQ * SEQ * 2);   // 32MB
  unsigned short* attO = (unsigned short*)alloc((size_t)2048 * 512 * 2);
  float*          t1x  = (float*)alloc((size_t)2 * 2048 * 512 * 4);   // 16MB partials
  float*          y1   = (float*)alloc((size_t)2048 * 512 * 4);
  unsigned short* y1b  = (unsigned short*)alloc((size_t)2048 * 512 * 2);
  unsigned short* hbuf = rpep;                   // rpe dead after attention
  float*          oP   = t1x;                    // 8MB used during attn
  float*          lP   = (float*)y1b;            // y1b free during attn

  prep_all<<<4096, 256, 0, stream>>>(x, bq, bk, bv, xb, bqkv,
                                     Wq, Wk, Wv, Wo, F1, F2, qkvT, WoT, F1T, F2T);
  // fused rpe + QKV projection (768 gemm blocks + 2048 rpe blocks)
  rpe_qkv<<<2816, 256, 0, stream>>>(xb, qkvT, bqkv, Qhp, Khp, VTp,
                                    rel, R1, rb1, R2, rb2, rpep);
  attn_kernel<<<512, 256, 0, stream>>>(Qhp, Khp, VTp, rpep, oP, lP);
  attn_combine<<<2048, 256, 0, stream>>>(oP, lP, attO);

  // Wo: split-K x2 -> t1x partials (grid 512)
  gemm_k<EPI_F32, 64, 64, 2, 2><<<dim3(8, 32, 2), 256, 0, stream>>>(
      attO, WoT, bo, t1x, nullptr, nullptr, 2048, 512, 512, 4);
  ln_kernel<<<2048, 256, 0, stream>>>(t1x, t1x + (size_t)2048 * 512, x,
                                      g1, b1, y1, y1b);

  // FFN1: 64x64 tiles -> 1024 blocks
  gemm_k<EPI_GELU, 64, 64, 2, 2><<<dim3(32, 32, 1), 256, 0, stream>>>(
      y1b, F1T, fb1, hbuf, nullptr, nullptr, 2048, 2048, 512, 8);
  // FFN2: split-K x2 -> t1x partials (grid 512)
  gemm_k<EPI_F32, 64, 64, 2, 2><<<dim3(8, 32, 2), 256, 0, stream>>>(
      hbuf, F2T, fb2, t1x, nullptr, nullptr, 2048, 512, 2048, 16);
  ln_kernel<<<2048, 256, 0, stream>>>(t1x, t1x + (size_t)2048 * 512, y1,
                                      g2, b2, (float*)d_out, nullptr);
}